// Round 2
// baseline (214.173 us; speedup 1.0000x reference)
//
#include <hip/hip_runtime.h>
#include <hip/hip_bf16.h>

typedef short short4v __attribute__((ext_vector_type(4)));
typedef short short8v __attribute__((ext_vector_type(8)));
typedef float floatx4 __attribute__((ext_vector_type(4)));

#define SLEN 1024
#define DDIM 64
#define NBH  128
#define PSTR 72   // P_lds key-stride (64 + 8): b64 stores & b128 reads bank-optimal

__device__ __forceinline__ unsigned short f2bf(float f) {
  union { float f; unsigned int u; } v; v.f = f;
  unsigned int u = v.u;
  u += 0x7fffu + ((u >> 16) & 1u);   // RNE
  return (unsigned short)(u >> 16);
}

// packed fp32x2 -> bf16x2 (RNE); low short = first arg
__device__ __forceinline__ unsigned int pkbf(float a, float b) {
  __hip_bfloat162 h = __float22bfloat162_rn(float2{a, b});
  union { __hip_bfloat162 h; unsigned int u; } c; c.h = h;
  return c.u;
}

// ---------------- fused prepass ----------------
// blocks [0,4096): K fp32 -> bf16 plain row-major tiles (pure streaming convert)
// blocks [4096,4608): V fp32 -> bf16 transposed tiles [bh][ch][d][key] + per-chunk col sums
__global__ __launch_bounds__(256)
void prep_kv(const float* __restrict__ Kg, const float* __restrict__ Vg,
             unsigned short* __restrict__ wsK, unsigned short* __restrict__ wsVT,
             float* __restrict__ CS) {
  const int bx = blockIdx.x;
  if (bx < 4096) {
    const int t = bx * 256 + threadIdx.x;          // granule id (1,048,576)
    const float4 f0 = *(const float4*)(Kg + (size_t)t * 8);
    const float4 f1 = *(const float4*)(Kg + (size_t)t * 8 + 4);
    short8v s;
    s[0]=(short)f2bf(f0.x); s[1]=(short)f2bf(f0.y); s[2]=(short)f2bf(f0.z); s[3]=(short)f2bf(f0.w);
    s[4]=(short)f2bf(f1.x); s[5]=(short)f2bf(f1.y); s[6]=(short)f2bf(f1.z); s[7]=(short)f2bf(f1.w);
    *(short8v*)(wsK + (size_t)t * 8) = s;
  } else {
    const int w = threadIdx.x >> 6;
    const int d = threadIdx.x & 63;
    const int tile = (bx - 4096) * 4 + w;          // 2048 tiles (bh,ch)
    const int bh = tile >> 4, ch = tile & 15;
    const float* src = Vg + ((size_t)(bh * SLEN + ch * 64) * DDIM) + d;  // column d
    unsigned short* dst = wsVT + (size_t)tile * 4096 + d * 64;
    float sum = 0.f;
    #pragma unroll
    for (int gg = 0; gg < 8; ++gg) {
      short8v s;
      #pragma unroll
      for (int j = 0; j < 8; ++j) {
        const float x = src[(size_t)(gg * 8 + j) * DDIM];
        sum += x;
        s[j] = (short)f2bf(x);
      }
      *(short8v*)(dst + gg * 8) = s;
    }
    if (CS) CS[(size_t)tile * 64 + d] = sum;
  }
}

// ---------------- main: flash attention, no-max softmax (mask fill = 1e-6 => safe) ----
// Per-wave register staging of K/V fragments straight from the bf16 workspace:
// no K/V LDS, no barriers, no vmcnt convoy. All 4 waves read the same 16KB tile -> L1.
__global__ __launch_bounds__(256)
void attn_main(const float* __restrict__ Qg, const unsigned short* __restrict__ wsK,
               const unsigned short* __restrict__ wsVT, const float* __restrict__ CS,
               const int* __restrict__ vraw, float* __restrict__ Og)
{
  __shared__ unsigned short P_lds[4][32 * PSTR];  // per-wave P^T: [q][key]

  const int t  = threadIdx.x;
  const int w  = t >> 6;
  const int ln = t & 15;
  const int g  = (t >> 4) & 3;
  const int q0 = blockIdx.x * 128;
  const int bh = blockIdx.y;

  int vl;
  {
    const bool is64 = (vraw[1] == 0) && (vraw[3] == 0) && (vraw[5] == 0) && (vraw[7] == 0);
    const int b = bh >> 4;
    vl = is64 ? vraw[2 * b] : vraw[b];
  }
  const int full_ch     = vl >> 6;                 // chunks with all keys valid
  const int has_partial = (vl & 63) ? 1 : 0;
  const int nch         = CS ? (full_ch + has_partial) : 16;
  const int tail_start  = full_ch + has_partial;   // first fully-masked chunk

  // Q as B-operand fragments, pre-scaled by (1/8)*log2(e) so softmax = exp2.
  const float qs = 0.125f * 1.44269504f;
  short8v bq[2][2];
  #pragma unroll
  for (int nt = 0; nt < 2; ++nt) {
    const float* qp = Qg + ((size_t)bh * SLEN + q0 + w * 32 + nt * 16 + ln) * DDIM;
    #pragma unroll
    for (int st = 0; st < 2; ++st) {
      const float4 f0 = *(const float4*)(qp + st * 32 + g * 8);
      const float4 f1 = *(const float4*)(qp + st * 32 + g * 8 + 4);
      short8v a;
      a[0]=(short)f2bf(f0.x*qs); a[1]=(short)f2bf(f0.y*qs);
      a[2]=(short)f2bf(f0.z*qs); a[3]=(short)f2bf(f0.w*qs);
      a[4]=(short)f2bf(f1.x*qs); a[5]=(short)f2bf(f1.y*qs);
      a[6]=(short)f2bf(f1.z*qs); a[7]=(short)f2bf(f1.w*qs);
      bq[nt][st] = a;
    }
  }

  short8v ones;   // bf16 1.0 x8 : B-operand for row-sum MFMA
  #pragma unroll
  for (int j = 0; j < 8; ++j) ones[j] = (short)0x3F80;

  floatx4 o[2][4], lacc[2];
  #pragma unroll
  for (int m = 0; m < 2; ++m) {
    lacc[m] = (floatx4){0.f, 0.f, 0.f, 0.f};
    #pragma unroll
    for (int f = 0; f < 4; ++f) o[m][f] = (floatx4){0.f, 0.f, 0.f, 0.f};
  }

  const unsigned short* gk0 = wsK  + (size_t)bh * 16 * 4096;
  const unsigned short* gv0 = wsVT + (size_t)bh * 16 * 4096;

  for (int ch = 0; ch < nch; ++ch) {
    const unsigned short* gk = gk0 + (size_t)ch * 4096;
    const unsigned short* gv = gv0 + (size_t)ch * 4096;

    // ---- load K fragments for this wave (8 x 16B, coalesced 64B lines) ----
    short8v ak0[4], ak1[4];
    #pragma unroll
    for (int mt = 0; mt < 4; ++mt) {
      ak0[mt] = *(const short8v*)(gk + (mt * 16 + ln) * 64 + g * 8);
      ak1[mt] = *(const short8v*)(gk + (mt * 16 + ln) * 64 + 32 + g * 8);
    }

    // ---- S^T = K * Q^T : lane reg i holds key = mt*16+g*4+i, q = nt*16+ln ----
    floatx4 c[4][2];
    __builtin_amdgcn_s_setprio(1);
    #pragma unroll
    for (int mt = 0; mt < 4; ++mt) {
      #pragma unroll
      for (int nt = 0; nt < 2; ++nt) {
        floatx4 acc = (floatx4){0.f, 0.f, 0.f, 0.f};
        acc = __builtin_amdgcn_mfma_f32_16x16x32_bf16(ak0[mt], bq[nt][0], acc, 0, 0, 0);
        acc = __builtin_amdgcn_mfma_f32_16x16x32_bf16(ak1[mt], bq[nt][1], acc, 0, 0, 0);
        c[mt][nt] = acc;
      }
    }
    __builtin_amdgcn_s_setprio(0);

    // ---- issue V fragment loads now; latency hides under exp2/pack ----
    short8v av[2][4];
    #pragma unroll
    for (int st = 0; st < 2; ++st)
      #pragma unroll
      for (int f = 0; f < 4; ++f)
        av[st][f] = *(const short8v*)(gv + (f * 16 + ln) * 64 + st * 32 + g * 8);

    // ---- p = exp2(s) (masked -> exp2(0) = 1.0), packed cvt, b64 stores ----
    const bool fullv = (ch < full_ch);
    #pragma unroll
    for (int mt = 0; mt < 4; ++mt) {
      const int kg = ch * 64 + mt * 16 + g * 4;
      #pragma unroll
      for (int nt = 0; nt < 2; ++nt) {
        float p[4];
        if (fullv) {
          #pragma unroll
          for (int i = 0; i < 4; ++i) p[i] = __builtin_amdgcn_exp2f(c[mt][nt][i]);
        } else {
          #pragma unroll
          for (int i = 0; i < 4; ++i) {
            const float x = (kg + i < vl) ? c[mt][nt][i] : 0.0f;
            p[i] = __builtin_amdgcn_exp2f(x);
          }
        }
        union { short4v v; unsigned int u[2]; } pk;
        pk.u[0] = pkbf(p[0], p[1]);
        pk.u[1] = pkbf(p[2], p[3]);
        *(short4v*)&P_lds[w][(nt * 16 + ln) * PSTR + mt * 16 + g * 4] = pk.v;
      }
    }

    // ---- O += P*V ; l += P*ones (row-sum in C-layout, matches O rows) ----
    // P_lds is per-wave: ds_write -> ds_read ordering within a wave needs no barrier.
    #pragma unroll
    for (int st = 0; st < 2; ++st) {
      const short8v ap0 = *(const short8v*)&P_lds[w][(ln)      * PSTR + st * 32 + g * 8];
      const short8v ap1 = *(const short8v*)&P_lds[w][(16 + ln) * PSTR + st * 32 + g * 8];
      __builtin_amdgcn_s_setprio(1);
      lacc[0] = __builtin_amdgcn_mfma_f32_16x16x32_bf16(ap0, ones, lacc[0], 0, 0, 0);
      lacc[1] = __builtin_amdgcn_mfma_f32_16x16x32_bf16(ap1, ones, lacc[1], 0, 0, 0);
      #pragma unroll
      for (int f = 0; f < 4; ++f) {
        o[0][f] = __builtin_amdgcn_mfma_f32_16x16x32_bf16(ap0, av[st][f], o[0][f], 0, 0, 0);
        o[1][f] = __builtin_amdgcn_mfma_f32_16x16x32_bf16(ap1, av[st][f], o[1][f], 0, 0, 0);
      }
      __builtin_amdgcn_s_setprio(0);
    }
  }

  // ---- fully-masked tail: O += suffix colsum of V, l += #masked (p = 1.0 each) ----
  // CS holds per-chunk colsums; sum chunks tail_start..15 here (L2-resident, cheap).
  if (CS != nullptr && tail_start < 16) {
    float svf[4] = {0.f, 0.f, 0.f, 0.f};
    for (int ch = tail_start; ch < 16; ++ch) {
      const float* cs = CS + ((size_t)bh * 16 + ch) * 64;
      #pragma unroll
      for (int f = 0; f < 4; ++f) svf[f] += cs[f * 16 + ln];
    }
    const float ml = (float)(SLEN - tail_start * 64);
    #pragma unroll
    for (int m = 0; m < 2; ++m) {
      #pragma unroll
      for (int i = 0; i < 4; ++i) lacc[m][i] += ml;
      #pragma unroll
      for (int f = 0; f < 4; ++f)
        #pragma unroll
        for (int i = 0; i < 4; ++i) o[m][f][i] += svf[f];
    }
  }

  // ---- epilogue: O /= l (lacc is in C-layout: same rows as O, no LDS needed) ----
  #pragma unroll
  for (int m = 0; m < 2; ++m) {
    #pragma unroll
    for (int i = 0; i < 4; ++i) {
      const float inv = 1.0f / lacc[m][i];
      const size_t row = (size_t)bh * SLEN + q0 + w * 32 + m * 16 + g * 4 + i;
      #pragma unroll
      for (int f = 0; f < 4; ++f)
        Og[row * DDIM + f * 16 + ln] = o[m][f][i] * inv;
    }
  }
}

// ================= fallback (round-1 kernel, used only if ws too small) =================
#define KSTR 72
__device__ __forceinline__ float bf2f(unsigned short h) {
  union { unsigned int u; float f; } v; v.u = ((unsigned int)h) << 16;
  return v.f;
}
__global__ __launch_bounds__(256)
void attn_fwd_fallback(const float* __restrict__ Qg, const float* __restrict__ Kg,
                       const float* __restrict__ Vg, const int* __restrict__ vraw,
                       float* __restrict__ Og)
{
  __shared__ unsigned short K_lds[64 * KSTR];
  __shared__ unsigned short VT_lds[64 * KSTR];
  __shared__ unsigned short P_lds[4][32 * KSTR];
  const int t  = threadIdx.x;
  const int w  = t >> 6;
  const int ln = t & 15;
  const int g  = (t >> 4) & 3;
  const int q0 = blockIdx.x * 128;
  const int bh = blockIdx.y;
  int vl;
  {
    const bool is64 = (vraw[1] == 0) && (vraw[3] == 0) && (vraw[5] == 0) && (vraw[7] == 0);
    const int b = bh >> 4;
    vl = is64 ? vraw[2 * b] : vraw[b];
  }
  short8v aq[2][2];
  #pragma unroll
  for (int m = 0; m < 2; ++m) {
    const float* qp = Qg + ((size_t)bh * SLEN + q0 + w * 32 + m * 16 + ln) * DDIM;
    #pragma unroll
    for (int st = 0; st < 2; ++st) {
      const int d0 = st * 32 + g * 8;
      const float4 f0 = *(const float4*)(qp + d0);
      const float4 f1 = *(const float4*)(qp + d0 + 4);
      short8v a;
      a[0]=(short)f2bf(f0.x); a[1]=(short)f2bf(f0.y); a[2]=(short)f2bf(f0.z); a[3]=(short)f2bf(f0.w);
      a[4]=(short)f2bf(f1.x); a[5]=(short)f2bf(f1.y); a[6]=(short)f2bf(f1.z); a[7]=(short)f2bf(f1.w);
      aq[m][st] = a;
    }
  }
  float mrow[2][4], lrow[2][4];
  floatx4 o[2][4];
  #pragma unroll
  for (int m = 0; m < 2; ++m) {
    #pragma unroll
    for (int i = 0; i < 4; ++i) { mrow[m][i] = -INFINITY; lrow[m][i] = 0.f; }
    #pragma unroll
    for (int f = 0; f < 4; ++f) o[m][f] = (floatx4){0.f, 0.f, 0.f, 0.f};
  }
  const float scale = 0.125f;
  for (int ch = 0; ch < SLEN / 64; ++ch) {
    const int k0 = ch * 64;
    __syncthreads();
    {
      const int c4 = (t & 15) * 4;
      const int r0 = t >> 4;
      const float* kp = Kg + ((size_t)bh * SLEN + k0 + r0) * DDIM + c4;
      #pragma unroll
      for (int r = 0; r < 4; ++r) {
        const float4 v = *(const float4*)(kp + (size_t)(16 * r) * DDIM);
        short4v bq2;
        bq2[0]=(short)f2bf(v.x); bq2[1]=(short)f2bf(v.y); bq2[2]=(short)f2bf(v.z); bq2[3]=(short)f2bf(v.w);
        *(short4v*)&K_lds[(r0 + 16 * r) * KSTR + c4] = bq2;
      }
    }
    {
      const int kb = (t >> 4) * 4;
      const int db = (t & 15) * 4;
      const float* vp = Vg + ((size_t)bh * SLEN + k0 + kb) * DDIM + db;
      const float4 r0 = *(const float4*)(vp);
      const float4 r1 = *(const float4*)(vp + DDIM);
      const float4 r2 = *(const float4*)(vp + 2 * DDIM);
      const float4 r3 = *(const float4*)(vp + 3 * DDIM);
      short4v wa, wb, wc, wd;
      wa[0]=(short)f2bf(r0.x); wa[1]=(short)f2bf(r1.x); wa[2]=(short)f2bf(r2.x); wa[3]=(short)f2bf(r3.x);
      wb[0]=(short)f2bf(r0.y); wb[1]=(short)f2bf(r1.y); wb[2]=(short)f2bf(r2.y); wb[3]=(short)f2bf(r3.y);
      wc[0]=(short)f2bf(r0.z); wc[1]=(short)f2bf(r1.z); wc[2]=(short)f2bf(r2.z); wc[3]=(short)f2bf(r3.z);
      wd[0]=(short)f2bf(r0.w); wd[1]=(short)f2bf(r1.w); wd[2]=(short)f2bf(r2.w); wd[3]=(short)f2bf(r3.w);
      *(short4v*)&VT_lds[(db + 0) * KSTR + kb] = wa;
      *(short4v*)&VT_lds[(db + 1) * KSTR + kb] = wb;
      *(short4v*)&VT_lds[(db + 2) * KSTR + kb] = wc;
      *(short4v*)&VT_lds[(db + 3) * KSTR + kb] = wd;
    }
    __syncthreads();
    floatx4 c[2][4];
    #pragma unroll
    for (int m = 0; m < 2; ++m)
      #pragma unroll
      for (int f = 0; f < 4; ++f) c[m][f] = (floatx4){0.f, 0.f, 0.f, 0.f};
    #pragma unroll
    for (int f = 0; f < 4; ++f) {
      const short8v b0 = *(const short8v*)&K_lds[(16 * f + ln) * KSTR + g * 8];
      const short8v b1 = *(const short8v*)&K_lds[(16 * f + ln) * KSTR + 32 + g * 8];
      #pragma unroll
      for (int m = 0; m < 2; ++m) {
        c[m][f] = __builtin_amdgcn_mfma_f32_16x16x32_bf16(aq[m][0], b0, c[m][f], 0, 0, 0);
        c[m][f] = __builtin_amdgcn_mfma_f32_16x16x32_bf16(aq[m][1], b1, c[m][f], 0, 0, 0);
      }
    }
    #pragma unroll
    for (int m = 0; m < 2; ++m) {
      float s[4][4];
      #pragma unroll
      for (int f = 0; f < 4; ++f) {
        const int kgl = k0 + 16 * f + ln;
        const bool valid = kgl < vl;
        #pragma unroll
        for (int i = 0; i < 4; ++i)
          s[f][i] = valid ? c[m][f][i] * scale : 1e-6f;
      }
      #pragma unroll
      for (int i = 0; i < 4; ++i) {
        float r = fmaxf(fmaxf(s[0][i], s[1][i]), fmaxf(s[2][i], s[3][i]));
        r = fmaxf(r, __shfl_xor(r, 1));
        r = fmaxf(r, __shfl_xor(r, 2));
        r = fmaxf(r, __shfl_xor(r, 4));
        r = fmaxf(r, __shfl_xor(r, 8));
        const float mn = fmaxf(mrow[m][i], r);
        const float al = __expf(mrow[m][i] - mn);
        mrow[m][i] = mn;
        float rs = 0.f;
        #pragma unroll
        for (int f = 0; f < 4; ++f) {
          const unsigned short pb = f2bf(__expf(s[f][i] - mn));
          P_lds[w][(m * 16 + g * 4 + i) * KSTR + 16 * f + ln] = pb;
          rs += bf2f(pb);
        }
        rs += __shfl_xor(rs, 1);
        rs += __shfl_xor(rs, 2);
        rs += __shfl_xor(rs, 4);
        rs += __shfl_xor(rs, 8);
        lrow[m][i] = lrow[m][i] * al + rs;
        #pragma unroll
        for (int f = 0; f < 4; ++f) o[m][f][i] *= al;
      }
    }
    #pragma unroll
    for (int st = 0; st < 2; ++st) {
      const short8v ap0 = *(const short8v*)&P_lds[w][(ln)*KSTR + st * 32 + g * 8];
      const short8v ap1 = *(const short8v*)&P_lds[w][(16 + ln) * KSTR + st * 32 + g * 8];
      #pragma unroll
      for (int f = 0; f < 4; ++f) {
        const short8v bv = *(const short8v*)&VT_lds[(16 * f + ln) * KSTR + st * 32 + g * 8];
        o[0][f] = __builtin_amdgcn_mfma_f32_16x16x32_bf16(ap0, bv, o[0][f], 0, 0, 0);
        o[1][f] = __builtin_amdgcn_mfma_f32_16x16x32_bf16(ap1, bv, o[1][f], 0, 0, 0);
      }
    }
  }
  #pragma unroll
  for (int m = 0; m < 2; ++m) {
    float inv[4];
    #pragma unroll
    for (int i = 0; i < 4; ++i) inv[i] = 1.0f / lrow[m][i];
    #pragma unroll
    for (int f = 0; f < 4; ++f) {
      #pragma unroll
      for (int i = 0; i < 4; ++i) {
        const size_t row = (size_t)bh * SLEN + q0 + w * 32 + m * 16 + g * 4 + i;
        Og[row * DDIM + 16 * f + ln] = o[m][f][i] * inv[i];
      }
    }
  }
}

extern "C" void kernel_launch(void* const* d_in, const int* in_sizes, int n_in,
                              void* d_out, int out_size, void* d_ws, size_t ws_size,
                              hipStream_t stream) {
  const float* Q = (const float*)d_in[0];
  const float* K = (const float*)d_in[1];
  const float* V = (const float*)d_in[2];
  const int*  vl = (const int*)d_in[3];
  float* out = (float*)d_out;

  const size_t ws_kv = (size_t)2 * NBH * SLEN * DDIM * 2;      // 33,554,432 B (K+V bf16)
  const size_t ws_sv = ws_kv + (size_t)NBH * 16 * 64 * 4;      // +524,288 B (chunk colsums)

  if (ws_size >= ws_kv) {
    unsigned short* wsK  = (unsigned short*)d_ws;
    unsigned short* wsVT = wsK + (size_t)NBH * SLEN * DDIM;
    float* CS = (ws_size >= ws_sv) ? (float*)((char*)d_ws + ws_kv) : nullptr;
    prep_kv<<<4608, 256, 0, stream>>>(K, V, wsK, wsVT, CS);
    attn_main<<<dim3(SLEN / 128, NBH), dim3(256), 0, stream>>>(Q, wsK, wsVT, CS, vl, out);
  } else {
    attn_fwd_fallback<<<dim3(SLEN / 128, NBH), dim3(256), 0, stream>>>(Q, K, V, vl, out);
  }
}

// Round 3
// 194.707 us; speedup vs baseline: 1.1000x; 1.1000x over previous
//
#include <hip/hip_runtime.h>
#include <hip/hip_bf16.h>

typedef short short4v __attribute__((ext_vector_type(4)));
typedef short short8v __attribute__((ext_vector_type(8)));
typedef float floatx4 __attribute__((ext_vector_type(4)));
typedef unsigned int uint2v __attribute__((ext_vector_type(2)));

#define SLEN 1024
#define DDIM 64
#define NBH  128

__device__ __forceinline__ unsigned short f2bf(float f) {
  union { float f; unsigned int u; } v; v.f = f;
  unsigned int u = v.u;
  u += 0x7fffu + ((u >> 16) & 1u);   // RNE
  return (unsigned short)(u >> 16);
}

// packed fp32x2 -> bf16x2 (RNE); low short = first arg
__device__ __forceinline__ unsigned int pkbf(float a, float b) {
  __hip_bfloat162 h = __float22bfloat162_rn(float2{a, b});
  union { __hip_bfloat162 h; unsigned int u; } c; c.h = h;
  return c.u;
}

// cross-lane riffles (gfx950): a,b both updated.
// pl32: a' = [a_g0,a_g1,b_g0,b_g1], b' = [a_g2,a_g3,b_g2,b_g3]  (16-lane groups g0..g3)
// pl16: a' = [a_g0,b_g0,a_g2,b_g2], b' = [a_g1,b_g1,a_g3,b_g3]
__device__ __forceinline__ void pl32sw(unsigned int &a, unsigned int &b) {
#if __has_builtin(__builtin_amdgcn_permlane32_swap)
  uint2v r = __builtin_amdgcn_permlane32_swap(a, b, false, false);
  a = r[0]; b = r[1];
#else
  asm volatile("s_nop 1\n\tv_permlane32_swap_b32 %0, %1" : "+v"(a), "+v"(b));
#endif
}
__device__ __forceinline__ void pl16sw(unsigned int &a, unsigned int &b) {
#if __has_builtin(__builtin_amdgcn_permlane16_swap)
  uint2v r = __builtin_amdgcn_permlane16_swap(a, b, false, false);
  a = r[0]; b = r[1];
#else
  asm volatile("s_nop 1\n\tv_permlane16_swap_b32 %0, %1" : "+v"(a), "+v"(b));
#endif
}

// async global->LDS DMA, 16B per lane; LDS dest = wave-uniform base + lane*16
__device__ __forceinline__ void ld_lds16(const void* g, void* l) {
  __builtin_amdgcn_global_load_lds(
      (const __attribute__((address_space(1))) void*)g,
      (__attribute__((address_space(3))) void*)l, 16, 0, 0);
}

// ---------------- fused prepass (one launch) ----------------
// blocks [0,4096): K fp32 -> bf16 SWIZZLED tiles [bh][ch](64key x 64d)
//   granule gr of row r stored at r*128B + ((gr^(r&7))*16)B
// blocks [4096,4608): V fp32 -> bf16 transposed SWIZZLED tiles + per-chunk col sums
__global__ __launch_bounds__(256)
void prep_kv(const float* __restrict__ Kg, const float* __restrict__ Vg,
             unsigned short* __restrict__ wsK, unsigned short* __restrict__ wsVT,
             float* __restrict__ CS) {
  const int bx = blockIdx.x;
  if (bx < 4096) {
    const int t = bx * 256 + threadIdx.x;          // granule id (1,048,576)
    const int tile = t >> 9;
    const int q = t & 511;
    const int r = q >> 3, gr = q & 7;
    const float4 f0 = *(const float4*)(Kg + (size_t)t * 8);
    const float4 f1 = *(const float4*)(Kg + (size_t)t * 8 + 4);
    short8v s;
    s[0]=(short)f2bf(f0.x); s[1]=(short)f2bf(f0.y); s[2]=(short)f2bf(f0.z); s[3]=(short)f2bf(f0.w);
    s[4]=(short)f2bf(f1.x); s[5]=(short)f2bf(f1.y); s[6]=(short)f2bf(f1.z); s[7]=(short)f2bf(f1.w);
    *(short8v*)(wsK + (size_t)tile * 4096 + r * 64 + ((gr ^ (r & 7)) * 8)) = s;
  } else {
    const int w = threadIdx.x >> 6;
    const int d = threadIdx.x & 63;
    const int tile = (bx - 4096) * 4 + w;          // 2048 tiles (bh,ch)
    const int bh = tile >> 4, ch = tile & 15;
    const float* src = Vg + ((size_t)(bh * SLEN + ch * 64) * DDIM) + d;  // column d
    unsigned short* dst = wsVT + (size_t)tile * 4096 + d * 64;
    float sum = 0.f;
    #pragma unroll
    for (int gg = 0; gg < 8; ++gg) {
      short8v s;
      #pragma unroll
      for (int j = 0; j < 8; ++j) {
        const float x = src[(size_t)(gg * 8 + j) * DDIM];
        sum += x;
        s[j] = (short)f2bf(x);
      }
      *(short8v*)(dst + ((gg ^ (d & 7)) * 8)) = s;
    }
    if (CS) CS[(size_t)tile * 64 + d] = sum;
  }
}

// ---------------- main: flash attention, no-max softmax (mask fill = 1e-6 => safe) ----
// Round-1 DMA double-buffer pipeline restored; P_lds replaced by in-register
// permlane redistribution (T12): PV computed as O^T = V^T * P^T.
__global__ __launch_bounds__(256)
void attn_main(const float* __restrict__ Qg, const unsigned short* __restrict__ wsK,
               const unsigned short* __restrict__ wsVT, const float* __restrict__ CS,
               const int* __restrict__ vraw, float* __restrict__ Og)
{
  __shared__ unsigned short K_lds[2][4096];     // 64x64 bf16 swizzled, double-buffered
  __shared__ unsigned short VT_lds[2][4096];

  const int t  = threadIdx.x;
  const int ww = t >> 6;
  const int ln = t & 15;
  const int g  = (t >> 4) & 3;
  const int q0 = blockIdx.x * 128;
  const int bh = blockIdx.y;

  int vl;
  {
    const bool is64 = (vraw[1] == 0) && (vraw[3] == 0) && (vraw[5] == 0) && (vraw[7] == 0);
    const int b = bh >> 4;
    vl = is64 ? vraw[2 * b] : vraw[b];
  }
  const int full_ch     = vl >> 6;                 // chunks with all keys valid
  const int has_partial = (vl & 63) ? 1 : 0;
  const int nch         = CS ? (full_ch + has_partial) : 16;
  const int tail_start  = full_ch + has_partial;   // first fully-masked chunk

  // Q as B-operand fragments, pre-scaled by (1/8)*log2(e) so softmax = exp2.
  const float qs = 0.125f * 1.44269504f;
  short8v bq[2][2];
  #pragma unroll
  for (int nt = 0; nt < 2; ++nt) {
    const float* qp = Qg + ((size_t)bh * SLEN + q0 + ww * 32 + nt * 16 + ln) * DDIM;
    #pragma unroll
    for (int st = 0; st < 2; ++st) {
      const float4 f0 = *(const float4*)(qp + st * 32 + g * 8);
      const float4 f1 = *(const float4*)(qp + st * 32 + g * 8 + 4);
      short8v a;
      a[0]=(short)f2bf(f0.x*qs); a[1]=(short)f2bf(f0.y*qs);
      a[2]=(short)f2bf(f0.z*qs); a[3]=(short)f2bf(f0.w*qs);
      a[4]=(short)f2bf(f1.x*qs); a[5]=(short)f2bf(f1.y*qs);
      a[6]=(short)f2bf(f1.z*qs); a[7]=(short)f2bf(f1.w*qs);
      bq[nt][st] = a;
    }
  }

  const int l7  = ln & 7;
  const int sw0 = ((g) ^ l7) * 8;       // granule g   (keys/d 0..31 half)
  const int sw1 = ((4 + g) ^ l7) * 8;   // granule 4+g (keys/d 32..63 half)

  short8v ones;   // bf16 1.0 x8 : A-operand for row-sum MFMA (all rows equal)
  #pragma unroll
  for (int j = 0; j < 8; ++j) ones[j] = (short)0x3F80;

  // O^T fragments: ot[nt][f] holds O^T[d = f*16 + g*4 + i][q = nt*16 + ln]
  floatx4 ot[2][4], lacc[2];
  #pragma unroll
  for (int m = 0; m < 2; ++m) {
    lacc[m] = (floatx4){0.f, 0.f, 0.f, 0.f};
    #pragma unroll
    for (int f = 0; f < 4; ++f) ot[m][f] = (floatx4){0.f, 0.f, 0.f, 0.f};
  }

  const size_t tbase = (size_t)bh * 16 * 4096;
  auto issue = [&](int ch, int b) {
    const unsigned short* gk = wsK  + tbase + (size_t)ch * 4096;
    const unsigned short* gv = wsVT + tbase + (size_t)ch * 4096;
    ld_lds16(gk + (size_t)t * 8,         &K_lds[b][t * 8]);
    ld_lds16(gk + (size_t)(t + 256) * 8, &K_lds[b][(t + 256) * 8]);
    ld_lds16(gv + (size_t)t * 8,         &VT_lds[b][t * 8]);
    ld_lds16(gv + (size_t)(t + 256) * 8, &VT_lds[b][(t + 256) * 8]);
  };

  if (nch > 0) issue(0, 0);

  for (int ch = 0; ch < nch; ++ch) {
    const int b = ch & 1;
    if (ch + 1 < nch) {
      issue(ch + 1, b ^ 1);                    // prefetch next chunk (other buffer)
      __builtin_amdgcn_s_waitcnt(0x0f74);      // vmcnt(4): this chunk's 4 DMAs landed
    } else {
      __builtin_amdgcn_s_waitcnt(0x0f70);      // vmcnt(0)
    }
    __builtin_amdgcn_s_barrier();              // all waves' chunk-ch DMA landed

    // ---- S^T = K * Q^T : lane reg i holds key = mt*16+g*4+i, q = nt*16+ln ----
    floatx4 c[4][2];
    #pragma unroll
    for (int mt = 0; mt < 4; ++mt) {
      const short8v a0 = *(const short8v*)&K_lds[b][(mt * 16 + ln) * 64 + sw0];
      const short8v a1 = *(const short8v*)&K_lds[b][(mt * 16 + ln) * 64 + sw1];
      #pragma unroll
      for (int nt = 0; nt < 2; ++nt) {
        floatx4 acc = (floatx4){0.f, 0.f, 0.f, 0.f};
        acc = __builtin_amdgcn_mfma_f32_16x16x32_bf16(a0, bq[nt][0], acc, 0, 0, 0);
        acc = __builtin_amdgcn_mfma_f32_16x16x32_bf16(a1, bq[nt][1], acc, 0, 0, 0);
        c[mt][nt] = acc;
      }
    }

    // ---- p = exp2(s) (masked -> exp2(0) = 1.0), packed cvt to bf16 pairs ----
    unsigned int pk0[4][2], pk1[4][2];   // pk0 = keys {0,1}, pk1 = keys {2,3} of group
    const bool fullv = (ch < full_ch);
    #pragma unroll
    for (int mt = 0; mt < 4; ++mt) {
      const int kg = ch * 64 + mt * 16 + g * 4;
      #pragma unroll
      for (int nt = 0; nt < 2; ++nt) {
        float p[4];
        if (fullv) {
          #pragma unroll
          for (int i = 0; i < 4; ++i) p[i] = __builtin_amdgcn_exp2f(c[mt][nt][i]);
        } else {
          #pragma unroll
          for (int i = 0; i < 4; ++i) {
            const float x = (kg + i < vl) ? c[mt][nt][i] : 0.0f;
            p[i] = __builtin_amdgcn_exp2f(x);
          }
        }
        pk0[mt][nt] = pkbf(p[0], p[1]);
        pk1[mt][nt] = pkbf(p[2], p[3]);
      }
    }

    // ---- in-register P^T B-fragment build (replaces P_lds round-trip) ----
    // bp[st][nt]: lane(g,ln) holds P^T[k = st*32 + g*8 + j][q = nt*16 + ln], j=0..7
    short8v bp[2][2];
    #pragma unroll
    for (int st = 0; st < 2; ++st) {
      #pragma unroll
      for (int nt = 0; nt < 2; ++nt) {
        unsigned int a0 = pk0[2 * st][nt], b0 = pk0[2 * st + 1][nt];
        unsigned int a1 = pk1[2 * st][nt], b1 = pk1[2 * st + 1][nt];
        pl32sw(a0, b0); pl16sw(a0, b0);   // a0 -> keys {0,1}, b0 -> keys {4,5}
        pl32sw(a1, b1); pl16sw(a1, b1);   // a1 -> keys {2,3}, b1 -> keys {6,7}
        union { short8v s; unsigned int u[4]; } bb;
        bb.u[0] = a0; bb.u[1] = a1; bb.u[2] = b0; bb.u[3] = b1;
        bp[st][nt] = bb.s;
      }
    }

    // ---- O^T += V^T * P^T ; l += ones * P^T (all rows of lacc equal l_q) ----
    #pragma unroll
    for (int st = 0; st < 2; ++st) {
      lacc[0] = __builtin_amdgcn_mfma_f32_16x16x32_bf16(ones, bp[st][0], lacc[0], 0, 0, 0);
      lacc[1] = __builtin_amdgcn_mfma_f32_16x16x32_bf16(ones, bp[st][1], lacc[1], 0, 0, 0);
      const int sw = (st == 0) ? sw0 : sw1;
      #pragma unroll
      for (int f = 0; f < 4; ++f) {
        const short8v av = *(const short8v*)&VT_lds[b][(f * 16 + ln) * 64 + sw];
        ot[0][f] = __builtin_amdgcn_mfma_f32_16x16x32_bf16(av, bp[st][0], ot[0][f], 0, 0, 0);
        ot[1][f] = __builtin_amdgcn_mfma_f32_16x16x32_bf16(av, bp[st][1], ot[1][f], 0, 0, 0);
      }
    }

    if (ch + 1 < nch) __builtin_amdgcn_s_barrier();  // reads of buf b done before reuse
  }

  // ---- fully-masked tail: O^T += suffix colsum of V, l += #masked (p = 1.0 each) ----
  if (CS != nullptr && tail_start < 16) {
    floatx4 sv4[4];
    #pragma unroll
    for (int f = 0; f < 4; ++f) sv4[f] = (floatx4){0.f, 0.f, 0.f, 0.f};
    for (int ch2 = tail_start; ch2 < 16; ++ch2) {
      const float* cs = CS + ((size_t)bh * 16 + ch2) * 64 + g * 4;
      #pragma unroll
      for (int f = 0; f < 4; ++f) {
        const float4 v4 = *(const float4*)(cs + f * 16);
        sv4[f][0] += v4.x; sv4[f][1] += v4.y; sv4[f][2] += v4.z; sv4[f][3] += v4.w;
      }
    }
    const float ml = (float)(SLEN - tail_start * 64);
    #pragma unroll
    for (int nt = 0; nt < 2; ++nt) {
      #pragma unroll
      for (int i = 0; i < 4; ++i) lacc[nt][i] += ml;
      #pragma unroll
      for (int f = 0; f < 4; ++f)
        #pragma unroll
        for (int i = 0; i < 4; ++i) ot[nt][f][i] += sv4[f][i];
    }
  }

  // ---- epilogue: O = O^T / l ; lane writes float4 (4 consecutive d) per (nt,f) ----
  #pragma unroll
  for (int nt = 0; nt < 2; ++nt) {
    const float inv = 1.0f / lacc[nt][0];
    float* orow = Og + ((size_t)bh * SLEN + q0 + ww * 32 + nt * 16 + ln) * DDIM + g * 4;
    #pragma unroll
    for (int f = 0; f < 4; ++f) {
      float4 v4;
      v4.x = ot[nt][f][0] * inv; v4.y = ot[nt][f][1] * inv;
      v4.z = ot[nt][f][2] * inv; v4.w = ot[nt][f][3] * inv;
      *(float4*)(orow + f * 16) = v4;
    }
  }
}

// ================= fallback (round-1 kernel, used only if ws too small) =================
#define KSTR 72
__device__ __forceinline__ float bf2f(unsigned short h) {
  union { unsigned int u; float f; } v; v.u = ((unsigned int)h) << 16;
  return v.f;
}
__global__ __launch_bounds__(256)
void attn_fwd_fallback(const float* __restrict__ Qg, const float* __restrict__ Kg,
                       const float* __restrict__ Vg, const int* __restrict__ vraw,
                       float* __restrict__ Og)
{
  __shared__ unsigned short K_lds[64 * KSTR];
  __shared__ unsigned short VT_lds[64 * KSTR];
  __shared__ unsigned short P_lds[4][32 * KSTR];
  const int t  = threadIdx.x;
  const int w  = t >> 6;
  const int ln = t & 15;
  const int g  = (t >> 4) & 3;
  const int q0 = blockIdx.x * 128;
  const int bh = blockIdx.y;
  int vl;
  {
    const bool is64 = (vraw[1] == 0) && (vraw[3] == 0) && (vraw[5] == 0) && (vraw[7] == 0);
    const int b = bh >> 4;
    vl = is64 ? vraw[2 * b] : vraw[b];
  }
  short8v aq[2][2];
  #pragma unroll
  for (int m = 0; m < 2; ++m) {
    const float* qp = Qg + ((size_t)bh * SLEN + q0 + w * 32 + m * 16 + ln) * DDIM;
    #pragma unroll
    for (int st = 0; st < 2; ++st) {
      const int d0 = st * 32 + g * 8;
      const float4 f0 = *(const float4*)(qp + d0);
      const float4 f1 = *(const float4*)(qp + d0 + 4);
      short8v a;
      a[0]=(short)f2bf(f0.x); a[1]=(short)f2bf(f0.y); a[2]=(short)f2bf(f0.z); a[3]=(short)f2bf(f0.w);
      a[4]=(short)f2bf(f1.x); a[5]=(short)f2bf(f1.y); a[6]=(short)f2bf(f1.z); a[7]=(short)f2bf(f1.w);
      aq[m][st] = a;
    }
  }
  float mrow[2][4], lrow[2][4];
  floatx4 o[2][4];
  #pragma unroll
  for (int m = 0; m < 2; ++m) {
    #pragma unroll
    for (int i = 0; i < 4; ++i) { mrow[m][i] = -INFINITY; lrow[m][i] = 0.f; }
    #pragma unroll
    for (int f = 0; f < 4; ++f) o[m][f] = (floatx4){0.f, 0.f, 0.f, 0.f};
  }
  const float scale = 0.125f;
  for (int ch = 0; ch < SLEN / 64; ++ch) {
    const int k0 = ch * 64;
    __syncthreads();
    {
      const int c4 = (t & 15) * 4;
      const int r0 = t >> 4;
      const float* kp = Kg + ((size_t)bh * SLEN + k0 + r0) * DDIM + c4;
      #pragma unroll
      for (int r = 0; r < 4; ++r) {
        const float4 v = *(const float4*)(kp + (size_t)(16 * r) * DDIM);
        short4v bq2;
        bq2[0]=(short)f2bf(v.x); bq2[1]=(short)f2bf(v.y); bq2[2]=(short)f2bf(v.z); bq2[3]=(short)f2bf(v.w);
        *(short4v*)&K_lds[(r0 + 16 * r) * KSTR + c4] = bq2;
      }
    }
    {
      const int kb = (t >> 4) * 4;
      const int db = (t & 15) * 4;
      const float* vp = Vg + ((size_t)bh * SLEN + k0 + kb) * DDIM + db;
      const float4 r0 = *(const float4*)(vp);
      const float4 r1 = *(const float4*)(vp + DDIM);
      const float4 r2 = *(const float4*)(vp + 2 * DDIM);
      const float4 r3 = *(const float4*)(vp + 3 * DDIM);
      short4v wa, wb, wc, wd;
      wa[0]=(short)f2bf(r0.x); wa[1]=(short)f2bf(r1.x); wa[2]=(short)f2bf(r2.x); wa[3]=(short)f2bf(r3.x);
      wb[0]=(short)f2bf(r0.y); wb[1]=(short)f2bf(r1.y); wb[2]=(short)f2bf(r2.y); wb[3]=(short)f2bf(r3.y);
      wc[0]=(short)f2bf(r0.z); wc[1]=(short)f2bf(r1.z); wc[2]=(short)f2bf(r2.z); wc[3]=(short)f2bf(r3.z);
      wd[0]=(short)f2bf(r0.w); wd[1]=(short)f2bf(r1.w); wd[2]=(short)f2bf(r2.w); wd[3]=(short)f2bf(r3.w);
      *(short4v*)&VT_lds[(db + 0) * KSTR + kb] = wa;
      *(short4v*)&VT_lds[(db + 1) * KSTR + kb] = wb;
      *(short4v*)&VT_lds[(db + 2) * KSTR + kb] = wc;
      *(short4v*)&VT_lds[(db + 3) * KSTR + kb] = wd;
    }
    __syncthreads();
    floatx4 c[2][4];
    #pragma unroll
    for (int m = 0; m < 2; ++m)
      #pragma unroll
      for (int f = 0; f < 4; ++f) c[m][f] = (floatx4){0.f, 0.f, 0.f, 0.f};
    #pragma unroll
    for (int f = 0; f < 4; ++f) {
      const short8v b0 = *(const short8v*)&K_lds[(16 * f + ln) * KSTR + g * 8];
      const short8v b1 = *(const short8v*)&K_lds[(16 * f + ln) * KSTR + 32 + g * 8];
      #pragma unroll
      for (int m = 0; m < 2; ++m) {
        c[m][f] = __builtin_amdgcn_mfma_f32_16x16x32_bf16(aq[m][0], b0, c[m][f], 0, 0, 0);
        c[m][f] = __builtin_amdgcn_mfma_f32_16x16x32_bf16(aq[m][1], b1, c[m][f], 0, 0, 0);
      }
    }
    #pragma unroll
    for (int m = 0; m < 2; ++m) {
      float s[4][4];
      #pragma unroll
      for (int f = 0; f < 4; ++f) {
        const int kgl = k0 + 16 * f + ln;
        const bool valid = kgl < vl;
        #pragma unroll
        for (int i = 0; i < 4; ++i)
          s[f][i] = valid ? c[m][f][i] * scale : 1e-6f;
      }
      #pragma unroll
      for (int i = 0; i < 4; ++i) {
        float r = fmaxf(fmaxf(s[0][i], s[1][i]), fmaxf(s[2][i], s[3][i]));
        r = fmaxf(r, __shfl_xor(r, 1));
        r = fmaxf(r, __shfl_xor(r, 2));
        r = fmaxf(r, __shfl_xor(r, 4));
        r = fmaxf(r, __shfl_xor(r, 8));
        const float mn = fmaxf(mrow[m][i], r);
        const float al = __expf(mrow[m][i] - mn);
        mrow[m][i] = mn;
        float rs = 0.f;
        #pragma unroll
        for (int f = 0; f < 4; ++f) {
          const unsigned short pb = f2bf(__expf(s[f][i] - mn));
          P_lds[w][(m * 16 + g * 4 + i) * KSTR + 16 * f + ln] = pb;
          rs += bf2f(pb);
        }
        rs += __shfl_xor(rs, 1);
        rs += __shfl_xor(rs, 2);
        rs += __shfl_xor(rs, 4);
        rs += __shfl_xor(rs, 8);
        lrow[m][i] = lrow[m][i] * al + rs;
        #pragma unroll
        for (int f = 0; f < 4; ++f) o[m][f][i] *= al;
      }
    }
    #pragma unroll
    for (int st = 0; st < 2; ++st) {
      const short8v ap0 = *(const short8v*)&P_lds[w][(ln)*KSTR + st * 32 + g * 8];
      const short8v ap1 = *(const short8v*)&P_lds[w][(16 + ln) * KSTR + st * 32 + g * 8];
      #pragma unroll
      for (int f = 0; f < 4; ++f) {
        const short8v bv = *(const short8v*)&VT_lds[(16 * f + ln) * KSTR + st * 32 + g * 8];
        o[0][f] = __builtin_amdgcn_mfma_f32_16x16x32_bf16(ap0, bv, o[0][f], 0, 0, 0);
        o[1][f] = __builtin_amdgcn_mfma_f32_16x16x32_bf16(ap1, bv, o[1][f], 0, 0, 0);
      }
    }
  }
  #pragma unroll
  for (int m = 0; m < 2; ++m) {
    float inv[4];
    #pragma unroll
    for (int i = 0; i < 4; ++i) inv[i] = 1.0f / lrow[m][i];
    #pragma unroll
    for (int f = 0; f < 4; ++f) {
      #pragma unroll
      for (int i = 0; i < 4; ++i) {
        const size_t row = (size_t)bh * SLEN + q0 + w * 32 + m * 16 + g * 4 + i;
        Og[row * DDIM + 16 * f + ln] = o[m][f][i] * inv[i];
      }
    }
  }
}

extern "C" void kernel_launch(void* const* d_in, const int* in_sizes, int n_in,
                              void* d_out, int out_size, void* d_ws, size_t ws_size,
                              hipStream_t stream) {
  const float* Q = (const float*)d_in[0];
  const float* K = (const float*)d_in[1];
  const float* V = (const float*)d_in[2];
  const int*  vl = (const int*)d_in[3];
  float* out = (float*)d_out;

  const size_t ws_kv = (size_t)2 * NBH * SLEN * DDIM * 2;      // 33,554,432 B (K+V bf16)
  const size_t ws_sv = ws_kv + (size_t)NBH * 16 * 64 * 4;      // +524,288 B (chunk colsums)

  if (ws_size >= ws_kv) {
    unsigned short* wsK  = (unsigned short*)d_ws;
    unsigned short* wsVT = wsK + (size_t)NBH * SLEN * DDIM;
    float* CS = (ws_size >= ws_sv) ? (float*)((char*)d_ws + ws_kv) : nullptr;
    prep_kv<<<4608, 256, 0, stream>>>(K, V, wsK, wsVT, CS);
    attn_main<<<dim3(SLEN / 128, NBH), dim3(256), 0, stream>>>(Q, wsK, wsVT, CS, vl, out);
  } else {
    attn_fwd_fallback<<<dim3(SLEN / 128, NBH), dim3(256), 0, stream>>>(Q, K, V, vl, out);
  }
}

// Round 4
// 181.530 us; speedup vs baseline: 1.1798x; 1.0726x over previous
//
#include <hip/hip_runtime.h>
#include <hip/hip_bf16.h>

typedef short short4v __attribute__((ext_vector_type(4)));
typedef short short8v __attribute__((ext_vector_type(8)));
typedef float floatx4 __attribute__((ext_vector_type(4)));
typedef unsigned int uint2v __attribute__((ext_vector_type(2)));

#define SLEN 1024
#define DDIM 64
#define NBH  128

__device__ __forceinline__ unsigned short f2bf(float f) {
  union { float f; unsigned int u; } v; v.f = f;
  unsigned int u = v.u;
  u += 0x7fffu + ((u >> 16) & 1u);   // RNE
  return (unsigned short)(u >> 16);
}

// packed fp32x2 -> bf16x2 (RNE); low short = first arg
__device__ __forceinline__ unsigned int pkbf(float a, float b) {
  __hip_bfloat162 h = __float22bfloat162_rn(float2{a, b});
  union { __hip_bfloat162 h; unsigned int u; } c; c.h = h;
  return c.u;
}

// cross-lane riffles (gfx950): a,b both updated.
__device__ __forceinline__ void pl32sw(unsigned int &a, unsigned int &b) {
#if __has_builtin(__builtin_amdgcn_permlane32_swap)
  uint2v r = __builtin_amdgcn_permlane32_swap(a, b, false, false);
  a = r[0]; b = r[1];
#else
  asm volatile("s_nop 1\n\tv_permlane32_swap_b32 %0, %1" : "+v"(a), "+v"(b));
#endif
}
__device__ __forceinline__ void pl16sw(unsigned int &a, unsigned int &b) {
#if __has_builtin(__builtin_amdgcn_permlane16_swap)
  uint2v r = __builtin_amdgcn_permlane16_swap(a, b, false, false);
  a = r[0]; b = r[1];
#else
  asm volatile("s_nop 1\n\tv_permlane16_swap_b32 %0, %1" : "+v"(a), "+v"(b));
#endif
}

// async global->LDS DMA, 16B per lane; LDS dest = wave-uniform base + lane*16
__device__ __forceinline__ void ld_lds16(const void* g, void* l) {
  __builtin_amdgcn_global_load_lds(
      (const __attribute__((address_space(1))) void*)g,
      (__attribute__((address_space(3))) void*)l, 16, 0, 0);
}

__device__ __forceinline__ int decode_vl(const int* __restrict__ vraw, int bh) {
  const bool is64 = (vraw[1] == 0) && (vraw[3] == 0) && (vraw[5] == 0) && (vraw[7] == 0);
  const int b = bh >> 4;
  return is64 ? vraw[2 * b] : vraw[b];
}

// ---------------- fused prepass (one launch) ----------------
// blocks [0,4096): K fp32 -> bf16 SWIZZLED tiles [bh][ch](64key x 64d)
//   granule gr of row r stored at r*128B + ((gr^(r&7))*16)B
//   SKIPPED entirely for fully-masked chunks (never read by attn) when do_skip.
// blocks [4096,4608): V fp32 -> bf16 transposed SWIZZLED tiles + per-chunk col sums
//   bf16 write skipped for fully-masked chunks; col sums always written.
__global__ __launch_bounds__(256)
void prep_kv(const float* __restrict__ Kg, const float* __restrict__ Vg,
             unsigned short* __restrict__ wsK, unsigned short* __restrict__ wsVT,
             float* __restrict__ CS, const int* __restrict__ vraw, int do_skip) {
  const int bx = blockIdx.x;
  if (bx < 4096) {
    const int tile = bx >> 1;                      // 2 blocks per 64x64 tile
    if (do_skip) {
      const int bh = tile >> 4, ch = tile & 15;
      const int vl = decode_vl(vraw, bh);
      const int nch = (vl >> 6) + ((vl & 63) ? 1 : 0);
      if (ch >= nch) return;                       // tile never read by attn
    }
    const int t = bx * 256 + threadIdx.x;          // granule id
    const int q = t & 511;
    const int r = q >> 3, gr = q & 7;
    const float4 f0 = *(const float4*)(Kg + (size_t)t * 8);
    const float4 f1 = *(const float4*)(Kg + (size_t)t * 8 + 4);
    short8v s;
    s[0]=(short)f2bf(f0.x); s[1]=(short)f2bf(f0.y); s[2]=(short)f2bf(f0.z); s[3]=(short)f2bf(f0.w);
    s[4]=(short)f2bf(f1.x); s[5]=(short)f2bf(f1.y); s[6]=(short)f2bf(f1.z); s[7]=(short)f2bf(f1.w);
    *(short8v*)(wsK + (size_t)tile * 4096 + r * 64 + ((gr ^ (r & 7)) * 8)) = s;
  } else {
    const int w = threadIdx.x >> 6;
    const int d = threadIdx.x & 63;
    const int tile = (bx - 4096) * 4 + w;          // 2048 tiles (bh,ch)
    const int bh = tile >> 4, ch = tile & 15;
    bool do_store = true;
    if (do_skip) {
      const int vl = decode_vl(vraw, bh);
      const int nch = (vl >> 6) + ((vl & 63) ? 1 : 0);
      do_store = (ch < nch);
    }
    const float* src = Vg + ((size_t)(bh * SLEN + ch * 64) * DDIM) + d;  // column d
    unsigned short* dst = wsVT + (size_t)tile * 4096 + d * 64;
    float sum = 0.f;
    #pragma unroll
    for (int gg = 0; gg < 8; ++gg) {
      short8v s;
      #pragma unroll
      for (int j = 0; j < 8; ++j) {
        const float x = src[(size_t)(gg * 8 + j) * DDIM];
        sum += x;
        s[j] = (short)f2bf(x);
      }
      if (do_store) *(short8v*)(dst + ((gg ^ (d & 7)) * 8)) = s;
    }
    if (CS) CS[(size_t)tile * 64 + d] = sum;
  }
}

// -------- prepass: per-chunk col sums -> suffix sums in place (SV[ch] = sum ch..15) ----
__global__ __launch_bounds__(64)
void prep_sv(float* __restrict__ CS) {
  const int bh = blockIdx.x;
  const int d  = threadIdx.x;
  float acc = 0.f;
  for (int ch = 15; ch >= 0; --ch) {
    const size_t idx = ((size_t)bh * 16 + ch) * 64 + d;
    acc += CS[idx];
    CS[idx] = acc;
  }
}

// ---------------- main: flash attention, no-max softmax (mask fill = 1e-6 => safe) ----
// Depth-2 K prefetch (triple buf) + depth-1.5 V prefetch (double buf), counted vmcnt
// (steady state vmcnt(6), never 0 mid-loop). XCD-local mapping: bh = bid&127 so all 8
// q-blocks of one bh share an XCD's L2 (16 bh x 128KB = 2MB < 4MB L2).
// P redistribution in-register via permlane (no P_lds); PV as O^T = V^T * P^T.
__global__ __launch_bounds__(256)
void attn_main(const float* __restrict__ Qg, const unsigned short* __restrict__ wsK,
               const unsigned short* __restrict__ wsVT, const float* __restrict__ SV,
               const int* __restrict__ vraw, float* __restrict__ Og)
{
  __shared__ unsigned short K_lds[3][4096];     // 64x64 bf16 swizzled, triple-buffered
  __shared__ unsigned short VT_lds[2][4096];    // double-buffered          (total 40KB)

  const int t  = threadIdx.x;
  const int ww = t >> 6;
  const int ln = t & 15;
  const int g  = (t >> 4) & 3;
  const int bh = blockIdx.x & 127;              // XCD-local: 128 % 8 == 0
  const int q0 = (blockIdx.x >> 7) * 128;

  const int vl          = decode_vl(vraw, bh);
  const int full_ch     = vl >> 6;                 // chunks with all keys valid
  const int has_partial = (vl & 63) ? 1 : 0;
  const int nch         = SV ? (full_ch + has_partial) : 16;
  const int tail_start  = full_ch + has_partial;   // first fully-masked chunk

  // Q as B-operand fragments, pre-scaled by (1/8)*log2(e) so softmax = exp2.
  const float qs = 0.125f * 1.44269504f;
  short8v bq[2][2];
  #pragma unroll
  for (int nt = 0; nt < 2; ++nt) {
    const float* qp = Qg + ((size_t)bh * SLEN + q0 + ww * 32 + nt * 16 + ln) * DDIM;
    #pragma unroll
    for (int st = 0; st < 2; ++st) {
      const float4 f0 = *(const float4*)(qp + st * 32 + g * 8);
      const float4 f1 = *(const float4*)(qp + st * 32 + g * 8 + 4);
      short8v a;
      a[0]=(short)f2bf(f0.x*qs); a[1]=(short)f2bf(f0.y*qs);
      a[2]=(short)f2bf(f0.z*qs); a[3]=(short)f2bf(f0.w*qs);
      a[4]=(short)f2bf(f1.x*qs); a[5]=(short)f2bf(f1.y*qs);
      a[6]=(short)f2bf(f1.z*qs); a[7]=(short)f2bf(f1.w*qs);
      bq[nt][st] = a;
    }
  }

  const int l7  = ln & 7;
  const int sw0 = ((g) ^ l7) * 8;       // granule g   (keys/d 0..31 half)
  const int sw1 = ((4 + g) ^ l7) * 8;   // granule 4+g (keys/d 32..63 half)

  short8v ones;   // bf16 1.0 x8 : A-operand for row-sum MFMA (all rows equal)
  #pragma unroll
  for (int j = 0; j < 8; ++j) ones[j] = (short)0x3F80;

  // O^T fragments: ot[nt][f] holds O^T[d = f*16 + g*4 + i][q = nt*16 + ln]
  floatx4 ot[2][4], lacc[2];
  #pragma unroll
  for (int m = 0; m < 2; ++m) {
    lacc[m] = (floatx4){0.f, 0.f, 0.f, 0.f};
    #pragma unroll
    for (int f = 0; f < 4; ++f) ot[m][f] = (floatx4){0.f, 0.f, 0.f, 0.f};
  }

  const size_t tbase = (size_t)bh * 16 * 4096;
  auto issueK = [&](int ch, int b) {
    const unsigned short* gk = wsK + tbase + (size_t)ch * 4096;
    ld_lds16(gk + (size_t)t * 8,         &K_lds[b][t * 8]);
    ld_lds16(gk + (size_t)(t + 256) * 8, &K_lds[b][(t + 256) * 8]);
  };
  auto issueV = [&](int ch, int b) {
    const unsigned short* gv = wsVT + tbase + (size_t)ch * 4096;
    ld_lds16(gv + (size_t)t * 8,         &VT_lds[b][t * 8]);
    ld_lds16(gv + (size_t)(t + 256) * 8, &VT_lds[b][(t + 256) * 8]);
  };

  // prologue: K0, V0, K1 (issue order matters for vmcnt accounting)
  if (nch > 0) { issueK(0, 0); issueV(0, 0); }
  if (nch > 1) issueK(1, 1);

  int kb = 0;                                   // K buffer = ch % 3
  for (int ch = 0; ch < nch; ++ch) {
    const int vb = ch & 1;
    // issue V(ch+1) then K(ch+2); their buffers were last read at iter ch-1,
    // protected by the trailing barrier of iter ch-1.
    if (ch + 1 < nch) issueV(ch + 1, vb ^ 1);
    if (ch + 2 < nch) { int k2 = kb + 2; if (k2 >= 3) k2 -= 3; issueK(ch + 2, k2); }
    // wait own DMAs of chunk ch: newer in-flight = K(ch+1),V(ch+1),K(ch+2)
    if (ch + 2 < nch)      __builtin_amdgcn_s_waitcnt(0x0f76);  // vmcnt(6)
    else if (ch + 1 < nch) __builtin_amdgcn_s_waitcnt(0x0f74);  // vmcnt(4)
    else                   __builtin_amdgcn_s_waitcnt(0x0f70);  // vmcnt(0)
    __builtin_amdgcn_s_barrier();              // all waves' chunk-ch DMA landed

    // ---- S^T = K * Q^T : lane reg i holds key = mt*16+g*4+i, q = nt*16+ln ----
    floatx4 c[4][2];
    __builtin_amdgcn_s_setprio(1);
    #pragma unroll
    for (int mt = 0; mt < 4; ++mt) {
      const short8v a0 = *(const short8v*)&K_lds[kb][(mt * 16 + ln) * 64 + sw0];
      const short8v a1 = *(const short8v*)&K_lds[kb][(mt * 16 + ln) * 64 + sw1];
      #pragma unroll
      for (int nt = 0; nt < 2; ++nt) {
        floatx4 acc = (floatx4){0.f, 0.f, 0.f, 0.f};
        acc = __builtin_amdgcn_mfma_f32_16x16x32_bf16(a0, bq[nt][0], acc, 0, 0, 0);
        acc = __builtin_amdgcn_mfma_f32_16x16x32_bf16(a1, bq[nt][1], acc, 0, 0, 0);
        c[mt][nt] = acc;
      }
    }
    __builtin_amdgcn_s_setprio(0);

    // ---- p = exp2(s) (masked -> exp2(0) = 1.0), packed cvt to bf16 pairs ----
    unsigned int pk0[4][2], pk1[4][2];   // pk0 = keys {0,1}, pk1 = keys {2,3} of group
    const bool fullv = (ch < full_ch);
    #pragma unroll
    for (int mt = 0; mt < 4; ++mt) {
      const int kg = ch * 64 + mt * 16 + g * 4;
      #pragma unroll
      for (int nt = 0; nt < 2; ++nt) {
        float p[4];
        if (fullv) {
          #pragma unroll
          for (int i = 0; i < 4; ++i) p[i] = __builtin_amdgcn_exp2f(c[mt][nt][i]);
        } else {
          #pragma unroll
          for (int i = 0; i < 4; ++i) {
            const float x = (kg + i < vl) ? c[mt][nt][i] : 0.0f;
            p[i] = __builtin_amdgcn_exp2f(x);
          }
        }
        pk0[mt][nt] = pkbf(p[0], p[1]);
        pk1[mt][nt] = pkbf(p[2], p[3]);
      }
    }

    // ---- in-register P^T B-fragment build (permlane riffles, no LDS) ----
    short8v bp[2][2];
    #pragma unroll
    for (int st = 0; st < 2; ++st) {
      #pragma unroll
      for (int nt = 0; nt < 2; ++nt) {
        unsigned int a0 = pk0[2 * st][nt], b0 = pk0[2 * st + 1][nt];
        unsigned int a1 = pk1[2 * st][nt], b1 = pk1[2 * st + 1][nt];
        pl32sw(a0, b0); pl16sw(a0, b0);   // a0 -> keys {0,1}, b0 -> keys {4,5}
        pl32sw(a1, b1); pl16sw(a1, b1);   // a1 -> keys {2,3}, b1 -> keys {6,7}
        union { short8v s; unsigned int u[4]; } bb;
        bb.u[0] = a0; bb.u[1] = a1; bb.u[2] = b0; bb.u[3] = b1;
        bp[st][nt] = bb.s;
      }
    }

    // ---- O^T += V^T * P^T ; l += ones * P^T (all rows of lacc equal l_q) ----
    __builtin_amdgcn_s_setprio(1);
    #pragma unroll
    for (int st = 0; st < 2; ++st) {
      lacc[0] = __builtin_amdgcn_mfma_f32_16x16x32_bf16(ones, bp[st][0], lacc[0], 0, 0, 0);
      lacc[1] = __builtin_amdgcn_mfma_f32_16x16x32_bf16(ones, bp[st][1], lacc[1], 0, 0, 0);
      const int sw = (st == 0) ? sw0 : sw1;
      #pragma unroll
      for (int f = 0; f < 4; ++f) {
        const short8v av = *(const short8v*)&VT_lds[vb][(f * 16 + ln) * 64 + sw];
        ot[0][f] = __builtin_amdgcn_mfma_f32_16x16x32_bf16(av, bp[st][0], ot[0][f], 0, 0, 0);
        ot[1][f] = __builtin_amdgcn_mfma_f32_16x16x32_bf16(av, bp[st][1], ot[1][f], 0, 0, 0);
      }
    }
    __builtin_amdgcn_s_setprio(0);

    if (ch + 1 < nch) __builtin_amdgcn_s_barrier();  // reads of bufs done before reuse
    kb = (kb == 2) ? 0 : kb + 1;
  }

  // ---- fully-masked tail: O^T += suffix colsum of V, l += #masked (p = 1.0 each) ----
  if (SV != nullptr && tail_start < 16) {
    const float* sv = SV + ((size_t)bh * 16 + tail_start) * 64 + g * 4;
    float4 sv4[4];
    #pragma unroll
    for (int f = 0; f < 4; ++f) sv4[f] = *(const float4*)(sv + f * 16);
    const float ml = (float)(SLEN - tail_start * 64);
    #pragma unroll
    for (int nt = 0; nt < 2; ++nt) {
      #pragma unroll
      for (int i = 0; i < 4; ++i) lacc[nt][i] += ml;
      #pragma unroll
      for (int f = 0; f < 4; ++f) {
        ot[nt][f][0] += sv4[f].x; ot[nt][f][1] += sv4[f].y;
        ot[nt][f][2] += sv4[f].z; ot[nt][f][3] += sv4[f].w;
      }
    }
  }

  // ---- epilogue: O = O^T / l ; lane writes float4 (4 consecutive d) per (nt,f) ----
  #pragma unroll
  for (int nt = 0; nt < 2; ++nt) {
    const float inv = 1.0f / lacc[nt][0];
    float* orow = Og + ((size_t)bh * SLEN + q0 + ww * 32 + nt * 16 + ln) * DDIM + g * 4;
    #pragma unroll
    for (int f = 0; f < 4; ++f) {
      float4 v4;
      v4.x = ot[nt][f][0] * inv; v4.y = ot[nt][f][1] * inv;
      v4.z = ot[nt][f][2] * inv; v4.w = ot[nt][f][3] * inv;
      *(float4*)(orow + f * 16) = v4;
    }
  }
}

// ================= fallback (round-1 kernel, used only if ws too small) =================
#define KSTR 72
__device__ __forceinline__ float bf2f(unsigned short h) {
  union { unsigned int u; float f; } v; v.u = ((unsigned int)h) << 16;
  return v.f;
}
__global__ __launch_bounds__(256)
void attn_fwd_fallback(const float* __restrict__ Qg, const float* __restrict__ Kg,
                       const float* __restrict__ Vg, const int* __restrict__ vraw,
                       float* __restrict__ Og)
{
  __shared__ unsigned short K_lds[64 * KSTR];
  __shared__ unsigned short VT_lds[64 * KSTR];
  __shared__ unsigned short P_lds[4][32 * KSTR];
  const int t  = threadIdx.x;
  const int w  = t >> 6;
  const int ln = t & 15;
  const int g  = (t >> 4) & 3;
  const int q0 = blockIdx.x * 128;
  const int bh = blockIdx.y;
  int vl;
  {
    const bool is64 = (vraw[1] == 0) && (vraw[3] == 0) && (vraw[5] == 0) && (vraw[7] == 0);
    const int b = bh >> 4;
    vl = is64 ? vraw[2 * b] : vraw[b];
  }
  short8v aq[2][2];
  #pragma unroll
  for (int m = 0; m < 2; ++m) {
    const float* qp = Qg + ((size_t)bh * SLEN + q0 + w * 32 + m * 16 + ln) * DDIM;
    #pragma unroll
    for (int st = 0; st < 2; ++st) {
      const int d0 = st * 32 + g * 8;
      const float4 f0 = *(const float4*)(qp + d0);
      const float4 f1 = *(const float4*)(qp + d0 + 4);
      short8v a;
      a[0]=(short)f2bf(f0.x); a[1]=(short)f2bf(f0.y); a[2]=(short)f2bf(f0.z); a[3]=(short)f2bf(f0.w);
      a[4]=(short)f2bf(f1.x); a[5]=(short)f2bf(f1.y); a[6]=(short)f2bf(f1.z); a[7]=(short)f2bf(f1.w);
      aq[m][st] = a;
    }
  }
  float mrow[2][4], lrow[2][4];
  floatx4 o[2][4];
  #pragma unroll
  for (int m = 0; m < 2; ++m) {
    #pragma unroll
    for (int i = 0; i < 4; ++i) { mrow[m][i] = -INFINITY; lrow[m][i] = 0.f; }
    #pragma unroll
    for (int f = 0; f < 4; ++f) o[m][f] = (floatx4){0.f, 0.f, 0.f, 0.f};
  }
  const float scale = 0.125f;
  for (int ch = 0; ch < SLEN / 64; ++ch) {
    const int k0 = ch * 64;
    __syncthreads();
    {
      const int c4 = (t & 15) * 4;
      const int r0 = t >> 4;
      const float* kp = Kg + ((size_t)bh * SLEN + k0 + r0) * DDIM + c4;
      #pragma unroll
      for (int r = 0; r < 4; ++r) {
        const float4 v = *(const float4*)(kp + (size_t)(16 * r) * DDIM);
        short4v bq2;
        bq2[0]=(short)f2bf(v.x); bq2[1]=(short)f2bf(v.y); bq2[2]=(short)f2bf(v.z); bq2[3]=(short)f2bf(v.w);
        *(short4v*)&K_lds[(r0 + 16 * r) * KSTR + c4] = bq2;
      }
    }
    {
      const int kb = (t >> 4) * 4;
      const int db = (t & 15) * 4;
      const float* vp = Vg + ((size_t)bh * SLEN + k0 + kb) * DDIM + db;
      const float4 r0 = *(const float4*)(vp);
      const float4 r1 = *(const float4*)(vp + DDIM);
      const float4 r2 = *(const float4*)(vp + 2 * DDIM);
      const float4 r3 = *(const float4*)(vp + 3 * DDIM);
      short4v wa, wb, wc, wd;
      wa[0]=(short)f2bf(r0.x); wa[1]=(short)f2bf(r1.x); wa[2]=(short)f2bf(r2.x); wa[3]=(short)f2bf(r3.x);
      wb[0]=(short)f2bf(r0.y); wb[1]=(short)f2bf(r1.y); wb[2]=(short)f2bf(r2.y); wb[3]=(short)f2bf(r3.y);
      wc[0]=(short)f2bf(r0.z); wc[1]=(short)f2bf(r1.z); wc[2]=(short)f2bf(r2.z); wc[3]=(short)f2bf(r3.z);
      wd[0]=(short)f2bf(r0.w); wd[1]=(short)f2bf(r1.w); wd[2]=(short)f2bf(r2.w); wd[3]=(short)f2bf(r3.w);
      *(short4v*)&VT_lds[(db + 0) * KSTR + kb] = wa;
      *(short4v*)&VT_lds[(db + 1) * KSTR + kb] = wb;
      *(short4v*)&VT_lds[(db + 2) * KSTR + kb] = wc;
      *(short4v*)&VT_lds[(db + 3) * KSTR + kb] = wd;
    }
    __syncthreads();
    floatx4 c[2][4];
    #pragma unroll
    for (int m = 0; m < 2; ++m)
      #pragma unroll
      for (int f = 0; f < 4; ++f) c[m][f] = (floatx4){0.f, 0.f, 0.f, 0.f};
    #pragma unroll
    for (int f = 0; f < 4; ++f) {
      const short8v b0 = *(const short8v*)&K_lds[(16 * f + ln) * KSTR + g * 8];
      const short8v b1 = *(const short8v*)&K_lds[(16 * f + ln) * KSTR + 32 + g * 8];
      #pragma unroll
      for (int m = 0; m < 2; ++m) {
        c[m][f] = __builtin_amdgcn_mfma_f32_16x16x32_bf16(aq[m][0], b0, c[m][f], 0, 0, 0);
        c[m][f] = __builtin_amdgcn_mfma_f32_16x16x32_bf16(aq[m][1], b1, c[m][f], 0, 0, 0);
      }
    }
    #pragma unroll
    for (int m = 0; m < 2; ++m) {
      float s[4][4];
      #pragma unroll
      for (int f = 0; f < 4; ++f) {
        const int kgl = k0 + 16 * f + ln;
        const bool valid = kgl < vl;
        #pragma unroll
        for (int i = 0; i < 4; ++i)
          s[f][i] = valid ? c[m][f][i] * scale : 1e-6f;
      }
      #pragma unroll
      for (int i = 0; i < 4; ++i) {
        float r = fmaxf(fmaxf(s[0][i], s[1][i]), fmaxf(s[2][i], s[3][i]));
        r = fmaxf(r, __shfl_xor(r, 1));
        r = fmaxf(r, __shfl_xor(r, 2));
        r = fmaxf(r, __shfl_xor(r, 4));
        r = fmaxf(r, __shfl_xor(r, 8));
        const float mn = fmaxf(mrow[m][i], r);
        const float al = __expf(mrow[m][i] - mn);
        mrow[m][i] = mn;
        float rs = 0.f;
        #pragma unroll
        for (int f = 0; f < 4; ++f) {
          const unsigned short pb = f2bf(__expf(s[f][i] - mn));
          P_lds[w][(m * 16 + g * 4 + i) * KSTR + 16 * f + ln] = pb;
          rs += bf2f(pb);
        }
        rs += __shfl_xor(rs, 1);
        rs += __shfl_xor(rs, 2);
        rs += __shfl_xor(rs, 4);
        rs += __shfl_xor(rs, 8);
        lrow[m][i] = lrow[m][i] * al + rs;
        #pragma unroll
        for (int f = 0; f < 4; ++f) o[m][f][i] *= al;
      }
    }
    #pragma unroll
    for (int st = 0; st < 2; ++st) {
      const short8v ap0 = *(const short8v*)&P_lds[w][(ln)*KSTR + st * 32 + g * 8];
      const short8v ap1 = *(const short8v*)&P_lds[w][(16 + ln) * KSTR + st * 32 + g * 8];
      #pragma unroll
      for (int f = 0; f < 4; ++f) {
        const short8v bv = *(const short8v*)&VT_lds[(16 * f + ln) * KSTR + st * 32 + g * 8];
        o[0][f] = __builtin_amdgcn_mfma_f32_16x16x32_bf16(ap0, bv, o[0][f], 0, 0, 0);
        o[1][f] = __builtin_amdgcn_mfma_f32_16x16x32_bf16(ap1, bv, o[1][f], 0, 0, 0);
      }
    }
  }
  #pragma unroll
  for (int m = 0; m < 2; ++m) {
    float inv[4];
    #pragma unroll
    for (int i = 0; i < 4; ++i) inv[i] = 1.0f / lrow[m][i];
    #pragma unroll
    for (int f = 0; f < 4; ++f) {
      #pragma unroll
      for (int i = 0; i < 4; ++i) {
        const size_t row = (size_t)bh * SLEN + q0 + w * 32 + m * 16 + g * 4 + i;
        Og[row * DDIM + 16 * f + ln] = o[m][f][i] * inv[i];
      }
    }
  }
}

extern "C" void kernel_launch(void* const* d_in, const int* in_sizes, int n_in,
                              void* d_out, int out_size, void* d_ws, size_t ws_size,
                              hipStream_t stream) {
  const float* Q = (const float*)d_in[0];
  const float* K = (const float*)d_in[1];
  const float* V = (const float*)d_in[2];
  const int*  vl = (const int*)d_in[3];
  float* out = (float*)d_out;

  const size_t ws_kv = (size_t)2 * NBH * SLEN * DDIM * 2;      // 33,554,432 B (K+V bf16)
  const size_t ws_sv = ws_kv + (size_t)NBH * 16 * 64 * 4;      // +524,288 B (chunk colsums)

  if (ws_size >= ws_kv) {
    unsigned short* wsK  = (unsigned short*)d_ws;
    unsigned short* wsVT = wsK + (size_t)NBH * SLEN * DDIM;
    float* CS = (ws_size >= ws_sv) ? (float*)((char*)d_ws + ws_kv) : nullptr;
    prep_kv<<<4608, 256, 0, stream>>>(K, V, wsK, wsVT, CS, vl, CS ? 1 : 0);
    if (CS) prep_sv<<<NBH, 64, 0, stream>>>(CS);
    attn_main<<<dim3(1024), dim3(256), 0, stream>>>(Q, wsK, wsVT, CS, vl, out);
  } else {
    attn_fwd_fallback<<<dim3(SLEN / 128, NBH), dim3(256), 0, stream>>>(Q, K, V, vl, out);
  }
}

// Round 6
// 178.204 us; speedup vs baseline: 1.2018x; 1.0187x over previous
//
#include <hip/hip_runtime.h>
#include <hip/hip_bf16.h>

typedef short short4v __attribute__((ext_vector_type(4)));
typedef short short8v __attribute__((ext_vector_type(8)));
typedef float floatx4 __attribute__((ext_vector_type(4)));

#define SLEN 1024
#define DDIM 64
#define NBH  128
#define PSTR 72   // P_lds key-stride (64 + 8): b64 stores & b128 reads bank-optimal

__device__ __forceinline__ unsigned short f2bf(float f) {
  union { float f; unsigned int u; } v; v.f = f;
  unsigned int u = v.u;
  u += 0x7fffu + ((u >> 16) & 1u);   // RNE
  return (unsigned short)(u >> 16);
}

// packed fp32x2 -> bf16x2 (RNE); low short = first arg
__device__ __forceinline__ unsigned int pkbf(float a, float b) {
  __hip_bfloat162 h = __float22bfloat162_rn(float2{a, b});
  union { __hip_bfloat162 h; unsigned int u; } c; c.h = h;
  return c.u;
}

// async global->LDS DMA, 16B per lane; LDS dest = wave-uniform base + lane*16
__device__ __forceinline__ void ld_lds16(const void* g, void* l) {
  __builtin_amdgcn_global_load_lds(
      (const __attribute__((address_space(1))) void*)g,
      (__attribute__((address_space(3))) void*)l, 16, 0, 0);
}

__device__ __forceinline__ int decode_vl(const int* __restrict__ vraw, int bh_or_b) {
  const bool is64 = (vraw[1] == 0) && (vraw[3] == 0) && (vraw[5] == 0) && (vraw[7] == 0);
  const int b = (bh_or_b >= 16) ? (bh_or_b >> 4) : (bh_or_b >> 4); // bh>>4 = batch
  return is64 ? vraw[2 * b] : vraw[b];
}

// ---------------- fused prepass (one launch) ----------------
// blocks [0,4096): K fp32 -> bf16 SWIZZLED tiles [bh][ch](64key x 64d)
//   granule gr of row r stored at r*128B + ((gr^(r&7))*16)B; skip masked chunks.
// blocks [4096,4608): V fp32 -> bf16 transposed SWIZZLED tiles + per-chunk col sums
__global__ __launch_bounds__(256)
void prep_kv(const float* __restrict__ Kg, const float* __restrict__ Vg,
             unsigned short* __restrict__ wsK, unsigned short* __restrict__ wsVT,
             float* __restrict__ CS, const int* __restrict__ vraw, int do_skip) {
  const int bx = blockIdx.x;
  if (bx < 4096) {
    const int tile = bx >> 1;                      // 2 blocks per 64x64 tile
    if (do_skip) {
      const int bh = tile >> 4, ch = tile & 15;
      const int vl = decode_vl(vraw, bh);
      const int nch = (vl >> 6) + ((vl & 63) ? 1 : 0);
      if (ch >= nch) return;                       // tile never read by attn
    }
    const int t = bx * 256 + threadIdx.x;          // granule id
    const int q = t & 511;
    const int r = q >> 3, gr = q & 7;
    const float4 f0 = *(const float4*)(Kg + (size_t)t * 8);
    const float4 f1 = *(const float4*)(Kg + (size_t)t * 8 + 4);
    short8v s;
    s[0]=(short)f2bf(f0.x); s[1]=(short)f2bf(f0.y); s[2]=(short)f2bf(f0.z); s[3]=(short)f2bf(f0.w);
    s[4]=(short)f2bf(f1.x); s[5]=(short)f2bf(f1.y); s[6]=(short)f2bf(f1.z); s[7]=(short)f2bf(f1.w);
    *(short8v*)(wsK + (size_t)(bx >> 1) * 4096 + r * 64 + ((gr ^ (r & 7)) * 8)) = s;
  } else {
    const int w = threadIdx.x >> 6;
    const int d = threadIdx.x & 63;
    const int tile = (bx - 4096) * 4 + w;          // 2048 tiles (bh,ch)
    const int bh = tile >> 4, ch = tile & 15;
    bool do_store = true;
    if (do_skip) {
      const int vl = decode_vl(vraw, bh);
      const int nch = (vl >> 6) + ((vl & 63) ? 1 : 0);
      do_store = (ch < nch);
    }
    const float* src = Vg + ((size_t)(bh * SLEN + ch * 64) * DDIM) + d;  // column d
    unsigned short* dst = wsVT + (size_t)tile * 4096 + d * 64;
    float sum = 0.f;
    #pragma unroll
    for (int gg = 0; gg < 8; ++gg) {
      short8v s;
      #pragma unroll
      for (int j = 0; j < 8; ++j) {
        const float x = src[(size_t)(gg * 8 + j) * DDIM];
        sum += x;
        s[j] = (short)f2bf(x);
      }
      if (do_store) *(short8v*)(dst + ((gg ^ (d & 7)) * 8)) = s;
    }
    if (CS) CS[(size_t)tile * 64 + d] = sum;
  }
}

// ---- prepass 2: (a) blocks 0..127: colsums -> suffix sums; (b) block 128: LPT sort ----
// SRT[x*16 + rank] = bh with rank-th largest nch among {bh : bh%8 == x}. Used by attn
// to snake-deal tasks so each CU's 4 blocks have near-equal total work (XCD-local kept).
__global__ __launch_bounds__(64)
void prep_sv(float* __restrict__ CS, const int* __restrict__ vraw, int* __restrict__ SRT) {
  const int blk = blockIdx.x;
  if (blk < NBH) {
    const int d = threadIdx.x;
    float acc = 0.f;
    for (int ch = 15; ch >= 0; --ch) {
      const size_t idx = ((size_t)blk * 16 + ch) * 64 + d;
      acc += CS[idx];
      CS[idx] = acc;
    }
  } else {
    const int x = threadIdx.x;
    if (x < 8) {
      int key[16];
      #pragma unroll
      for (int k = 0; k < 16; ++k) {
        const int vv = decode_vl(vraw, x + 8 * k);
        key[k] = (vv >> 6) + ((vv & 63) ? 1 : 0);
      }
      #pragma unroll
      for (int i = 0; i < 16; ++i) {
        int rank = 0;
        #pragma unroll
        for (int k2 = 0; k2 < 16; ++k2)
          rank += (int)((key[k2] > key[i]) || (key[k2] == key[i] && k2 < i));
        SRT[x * 16 + rank] = x + 8 * i;
      }
    }
  }
}

// ---------------- main: flash attention, no-max softmax (mask fill = 1e-6 => safe) ----
// Round-1 proven core (P_lds, depth-1 double-buffered DMA) + XCD-local bh mapping
// (bh = f(bid) with bh%8 == bid%8 -> K/V L2-resident per XCD) + LPT snake scheduling.
__global__ __launch_bounds__(256)
void attn_main(const float* __restrict__ Qg, const unsigned short* __restrict__ wsK,
               const unsigned short* __restrict__ wsVT, const float* __restrict__ SV,
               const int* __restrict__ SRT, const int* __restrict__ vraw,
               float* __restrict__ Og)
{
  __shared__ unsigned short K_lds[2][4096];     // 64x64 bf16 swizzled, double-buffered
  __shared__ unsigned short VT_lds[2][4096];
  __shared__ unsigned short P_lds[4][32 * PSTR];// per-wave P^T: [q][key]

  const int t  = threadIdx.x;
  const int w  = t >> 6;
  const int ln = t & 15;
  const int g  = (t >> 4) & 3;

  // task decode: XCD-local + LPT snake (assumes xcd=bid%8, cu=(bid>>3)%32, slot=bid>>8;
  // if the dispatch map differs, balance degrades to random -- never worse than static).
  int bh, q0;
  if (SRT) {
    const int xcd  = blockIdx.x & 7;
    const int lidx = blockIdx.x >> 3;
    const int cu   = lidx & 31;
    const int j    = lidx >> 5;                       // 0..3
    const int r    = j * 32 + ((j & 1) ? (31 - cu) : cu);
    bh = SRT[xcd * 16 + (r >> 3)];
    q0 = (r & 7) * 128;
  } else {
    bh = blockIdx.x & 127;
    q0 = (blockIdx.x >> 7) * 128;
  }

  const int vl          = decode_vl(vraw, bh);
  const int full_ch     = vl >> 6;                 // chunks with all keys valid
  const int has_partial = (vl & 63) ? 1 : 0;
  const int nch         = SV ? (full_ch + has_partial) : 16;
  const int tail_start  = full_ch + has_partial;   // first fully-masked chunk

  // Q as B-operand fragments, pre-scaled by (1/8)*log2(e) so softmax = exp2.
  const float qs = 0.125f * 1.44269504f;
  short8v bq[2][2];
  #pragma unroll
  for (int nt = 0; nt < 2; ++nt) {
    const float* qp = Qg + ((size_t)bh * SLEN + q0 + w * 32 + nt * 16 + ln) * DDIM;
    #pragma unroll
    for (int st = 0; st < 2; ++st) {
      const float4 f0 = *(const float4*)(qp + st * 32 + g * 8);
      const float4 f1 = *(const float4*)(qp + st * 32 + g * 8 + 4);
      short8v a;
      a[0]=(short)f2bf(f0.x*qs); a[1]=(short)f2bf(f0.y*qs);
      a[2]=(short)f2bf(f0.z*qs); a[3]=(short)f2bf(f0.w*qs);
      a[4]=(short)f2bf(f1.x*qs); a[5]=(short)f2bf(f1.y*qs);
      a[6]=(short)f2bf(f1.z*qs); a[7]=(short)f2bf(f1.w*qs);
      bq[nt][st] = a;
    }
  }

  const int l7  = ln & 7;
  const int sw0 = ((g) ^ l7) * 8;
  const int sw1 = ((4 + g) ^ l7) * 8;

  short8v ones;   // bf16 1.0 x8 : B-operand for row-sum MFMA
  #pragma unroll
  for (int j = 0; j < 8; ++j) ones[j] = (short)0x3F80;

  floatx4 o[2][4], lacc[2];
  #pragma unroll
  for (int m = 0; m < 2; ++m) {
    lacc[m] = (floatx4){0.f, 0.f, 0.f, 0.f};
    #pragma unroll
    for (int f = 0; f < 4; ++f) o[m][f] = (floatx4){0.f, 0.f, 0.f, 0.f};
  }

  const size_t tbase = (size_t)bh * 16 * 4096;
  auto issue = [&](int ch, int b) {
    const unsigned short* gk = wsK  + tbase + (size_t)ch * 4096;
    const unsigned short* gv = wsVT + tbase + (size_t)ch * 4096;
    ld_lds16(gk + (size_t)t * 8,         &K_lds[b][t * 8]);
    ld_lds16(gk + (size_t)(t + 256) * 8, &K_lds[b][(t + 256) * 8]);
    ld_lds16(gv + (size_t)t * 8,         &VT_lds[b][t * 8]);
    ld_lds16(gv + (size_t)(t + 256) * 8, &VT_lds[b][(t + 256) * 8]);
  };

  if (nch > 0) issue(0, 0);

  for (int ch = 0; ch < nch; ++ch) {
    const int b = ch & 1;
    if (ch + 1 < nch) {
      issue(ch + 1, b ^ 1);                    // prefetch next chunk (other buffer)
      __builtin_amdgcn_s_waitcnt(0x0f74);      // vmcnt(4): this chunk's 4 DMAs landed
    } else {
      __builtin_amdgcn_s_waitcnt(0x0f70);      // vmcnt(0)
    }
    __builtin_amdgcn_s_barrier();              // all waves' chunk-ch DMA landed

    // ---- S^T = K * Q^T : lane reg i holds key = mt*16+g*4+i, q = nt*16+ln ----
    floatx4 c[4][2];
    __builtin_amdgcn_s_setprio(1);
    #pragma unroll
    for (int mt = 0; mt < 4; ++mt) {
      const short8v a0 = *(const short8v*)&K_lds[b][(mt * 16 + ln) * 64 + sw0];
      const short8v a1 = *(const short8v*)&K_lds[b][(mt * 16 + ln) * 64 + sw1];
      #pragma unroll
      for (int nt = 0; nt < 2; ++nt) {
        floatx4 acc = (floatx4){0.f, 0.f, 0.f, 0.f};
        acc = __builtin_amdgcn_mfma_f32_16x16x32_bf16(a0, bq[nt][0], acc, 0, 0, 0);
        acc = __builtin_amdgcn_mfma_f32_16x16x32_bf16(a1, bq[nt][1], acc, 0, 0, 0);
        c[mt][nt] = acc;
      }
    }
    __builtin_amdgcn_s_setprio(0);

    // ---- p = exp2(s) (masked -> exp2(0) = 1.0), packed cvt, b64 stores ----
    const bool fullv = (ch < full_ch);
    #pragma unroll
    for (int mt = 0; mt < 4; ++mt) {
      const int kg = ch * 64 + mt * 16 + g * 4;
      #pragma unroll
      for (int nt = 0; nt < 2; ++nt) {
        float p[4];
        if (fullv) {
          #pragma unroll
          for (int i = 0; i < 4; ++i) p[i] = __builtin_amdgcn_exp2f(c[mt][nt][i]);
        } else {
          #pragma unroll
          for (int i = 0; i < 4; ++i) {
            const float x = (kg + i < vl) ? c[mt][nt][i] : 0.0f;
            p[i] = __builtin_amdgcn_exp2f(x);
          }
        }
        union { short4v v; unsigned int u[2]; } pk;
        pk.u[0] = pkbf(p[0], p[1]);
        pk.u[1] = pkbf(p[2], p[3]);
        *(short4v*)&P_lds[w][(nt * 16 + ln) * PSTR + mt * 16 + g * 4] = pk.v;
      }
    }

    // ---- O += P*V ; l += P*ones (row-sum in C-layout, matches O rows) ----
    #pragma unroll
    for (int st = 0; st < 2; ++st) {
      const short8v ap0 = *(const short8v*)&P_lds[w][(ln)      * PSTR + st * 32 + g * 8];
      const short8v ap1 = *(const short8v*)&P_lds[w][(16 + ln) * PSTR + st * 32 + g * 8];
      __builtin_amdgcn_s_setprio(1);
      lacc[0] = __builtin_amdgcn_mfma_f32_16x16x32_bf16(ap0, ones, lacc[0], 0, 0, 0);
      lacc[1] = __builtin_amdgcn_mfma_f32_16x16x32_bf16(ap1, ones, lacc[1], 0, 0, 0);
      const int sw = (st == 0) ? sw0 : sw1;
      #pragma unroll
      for (int f = 0; f < 4; ++f) {
        const short8v bv = *(const short8v*)&VT_lds[b][(f * 16 + ln) * 64 + sw];
        o[0][f] = __builtin_amdgcn_mfma_f32_16x16x32_bf16(ap0, bv, o[0][f], 0, 0, 0);
        o[1][f] = __builtin_amdgcn_mfma_f32_16x16x32_bf16(ap1, bv, o[1][f], 0, 0, 0);
      }
      __builtin_amdgcn_s_setprio(0);
    }

    if (ch + 1 < nch) __builtin_amdgcn_s_barrier();  // reads of buf b done before reuse
  }

  // ---- fully-masked tail: O += suffix colsum of V, l += #masked (p = 1.0 each) ----
  if (SV != nullptr && tail_start < 16) {
    const float* sv = SV + ((size_t)bh * 16 + tail_start) * 64;
    float svf[4];
    #pragma unroll
    for (int f = 0; f < 4; ++f) svf[f] = sv[f * 16 + ln];
    const float ml = (float)(SLEN - tail_start * 64);
    #pragma unroll
    for (int m = 0; m < 2; ++m) {
      #pragma unroll
      for (int i = 0; i < 4; ++i) lacc[m][i] += ml;
      #pragma unroll
      for (int f = 0; f < 4; ++f)
        #pragma unroll
        for (int i = 0; i < 4; ++i) o[m][f][i] += svf[f];
    }
  }

  // ---- epilogue: O /= l (lacc is in C-layout: same rows as O, no LDS needed) ----
  #pragma unroll
  for (int m = 0; m < 2; ++m) {
    #pragma unroll
    for (int i = 0; i < 4; ++i) {
      const float inv = 1.0f / lacc[m][i];
      const size_t row = (size_t)bh * SLEN + q0 + w * 32 + m * 16 + g * 4 + i;
      #pragma unroll
      for (int f = 0; f < 4; ++f)
        Og[row * DDIM + f * 16 + ln] = o[m][f][i] * inv;
    }
  }
}

// ================= fallback (round-1 kernel, used only if ws too small) =================
#define KSTR 72
__device__ __forceinline__ float bf2f(unsigned short h) {
  union { unsigned int u; float f; } v; v.u = ((unsigned int)h) << 16;
  return v.f;
}
__global__ __launch_bounds__(256)
void attn_fwd_fallback(const float* __restrict__ Qg, const float* __restrict__ Kg,
                       const float* __restrict__ Vg, const int* __restrict__ vraw,
                       float* __restrict__ Og)
{
  __shared__ unsigned short K_lds[64 * KSTR];
  __shared__ unsigned short VT_lds[64 * KSTR];
  __shared__ unsigned short P_lds[4][32 * KSTR];
  const int t  = threadIdx.x;
  const int w  = t >> 6;
  const int ln = t & 15;
  const int g  = (t >> 4) & 3;
  const int q0 = blockIdx.x * 128;
  const int bh = blockIdx.y;
  int vl;
  {
    const bool is64 = (vraw[1] == 0) && (vraw[3] == 0) && (vraw[5] == 0) && (vraw[7] == 0);
    const int b = bh >> 4;
    vl = is64 ? vraw[2 * b] : vraw[b];
  }
  short8v aq[2][2];
  #pragma unroll
  for (int m = 0; m < 2; ++m) {
    const float* qp = Qg + ((size_t)bh * SLEN + q0 + w * 32 + m * 16 + ln) * DDIM;
    #pragma unroll
    for (int st = 0; st < 2; ++st) {
      const int d0 = st * 32 + g * 8;
      const float4 f0 = *(const float4*)(qp + d0);
      const float4 f1 = *(const float4*)(qp + d0 + 4);
      short8v a;
      a[0]=(short)f2bf(f0.x); a[1]=(short)f2bf(f0.y); a[2]=(short)f2bf(f0.z); a[3]=(short)f2bf(f0.w);
      a[4]=(short)f2bf(f1.x); a[5]=(short)f2bf(f1.y); a[6]=(short)f2bf(f1.z); a[7]=(short)f2bf(f1.w);
      aq[m][st] = a;
    }
  }
  float mrow[2][4], lrow[2][4];
  floatx4 o[2][4];
  #pragma unroll
  for (int m = 0; m < 2; ++m) {
    #pragma unroll
    for (int i = 0; i < 4; ++i) { mrow[m][i] = -INFINITY; lrow[m][i] = 0.f; }
    #pragma unroll
    for (int f = 0; f < 4; ++f) o[m][f] = (floatx4){0.f, 0.f, 0.f, 0.f};
  }
  const float scale = 0.125f;
  for (int ch = 0; ch < SLEN / 64; ++ch) {
    const int k0 = ch * 64;
    __syncthreads();
    {
      const int c4 = (t & 15) * 4;
      const int r0 = t >> 4;
      const float* kp = Kg + ((size_t)bh * SLEN + k0 + r0) * DDIM + c4;
      #pragma unroll
      for (int r = 0; r < 4; ++r) {
        const float4 v = *(const float4*)(kp + (size_t)(16 * r) * DDIM);
        short4v bq2;
        bq2[0]=(short)f2bf(v.x); bq2[1]=(short)f2bf(v.y); bq2[2]=(short)f2bf(v.z); bq2[3]=(short)f2bf(v.w);
        *(short4v*)&K_lds[(r0 + 16 * r) * KSTR + c4] = bq2;
      }
    }
    {
      const int kb = (t >> 4) * 4;
      const int db = (t & 15) * 4;
      const float* vp = Vg + ((size_t)bh * SLEN + k0 + kb) * DDIM + db;
      const float4 r0 = *(const float4*)(vp);
      const float4 r1 = *(const float4*)(vp + DDIM);
      const float4 r2 = *(const float4*)(vp + 2 * DDIM);
      const float4 r3 = *(const float4*)(vp + 3 * DDIM);
      short4v wa, wb, wc, wd;
      wa[0]=(short)f2bf(r0.x); wa[1]=(short)f2bf(r1.x); wa[2]=(short)f2bf(r2.x); wa[3]=(short)f2bf(r3.x);
      wb[0]=(short)f2bf(r0.y); wb[1]=(short)f2bf(r1.y); wb[2]=(short)f2bf(r2.y); wb[3]=(short)f2bf(r3.y);
      wc[0]=(short)f2bf(r0.z); wc[1]=(short)f2bf(r1.z); wc[2]=(short)f2bf(r2.z); wc[3]=(short)f2bf(r3.z);
      wd[0]=(short)f2bf(r0.w); wd[1]=(short)f2bf(r1.w); wd[2]=(short)f2bf(r2.w); wd[3]=(short)f2bf(r3.w);
      *(short4v*)&VT_lds[(db + 0) * KSTR + kb] = wa;
      *(short4v*)&VT_lds[(db + 1) * KSTR + kb] = wb;
      *(short4v*)&VT_lds[(db + 2) * KSTR + kb] = wc;
      *(short4v*)&VT_lds[(db + 3) * KSTR + kb] = wd;
    }
    __syncthreads();
    floatx4 c[2][4];
    #pragma unroll
    for (int m = 0; m < 2; ++m)
      #pragma unroll
      for (int f = 0; f < 4; ++f) c[m][f] = (floatx4){0.f, 0.f, 0.f, 0.f};
    #pragma unroll
    for (int f = 0; f < 4; ++f) {
      const short8v b0 = *(const short8v*)&K_lds[(16 * f + ln) * KSTR + g * 8];
      const short8v b1 = *(const short8v*)&K_lds[(16 * f + ln) * KSTR + 32 + g * 8];
      #pragma unroll
      for (int m = 0; m < 2; ++m) {
        c[m][f] = __builtin_amdgcn_mfma_f32_16x16x32_bf16(aq[m][0], b0, c[m][f], 0, 0, 0);
        c[m][f] = __builtin_amdgcn_mfma_f32_16x16x32_bf16(aq[m][1], b1, c[m][f], 0, 0, 0);
      }
    }
    #pragma unroll
    for (int m = 0; m < 2; ++m) {
      float s[4][4];
      #pragma unroll
      for (int f = 0; f < 4; ++f) {
        const int kgl = k0 + 16 * f + ln;
        const bool valid = kgl < vl;
        #pragma unroll
        for (int i = 0; i < 4; ++i)
          s[f][i] = valid ? c[m][f][i] * scale : 1e-6f;
      }
      #pragma unroll
      for (int i = 0; i < 4; ++i) {
        float r = fmaxf(fmaxf(s[0][i], s[1][i]), fmaxf(s[2][i], s[3][i]));
        r = fmaxf(r, __shfl_xor(r, 1));
        r = fmaxf(r, __shfl_xor(r, 2));
        r = fmaxf(r, __shfl_xor(r, 4));
        r = fmaxf(r, __shfl_xor(r, 8));
        const float mn = fmaxf(mrow[m][i], r);
        const float al = __expf(mrow[m][i] - mn);
        mrow[m][i] = mn;
        float rs = 0.f;
        #pragma unroll
        for (int f = 0; f < 4; ++f) {
          const unsigned short pb = f2bf(__expf(s[f][i] - mn));
          P_lds[w][(m * 16 + g * 4 + i) * KSTR + 16 * f + ln] = pb;
          rs += bf2f(pb);
        }
        rs += __shfl_xor(rs, 1);
        rs += __shfl_xor(rs, 2);
        rs += __shfl_xor(rs, 4);
        rs += __shfl_xor(rs, 8);
        lrow[m][i] = lrow[m][i] * al + rs;
        #pragma unroll
        for (int f = 0; f < 4; ++f) o[m][f][i] *= al;
      }
    }
    #pragma unroll
    for (int st = 0; st < 2; ++st) {
      const short8v ap0 = *(const short8v*)&P_lds[w][(ln)*KSTR + st * 32 + g * 8];
      const short8v ap1 = *(const short8v*)&P_lds[w][(16 + ln) * KSTR + st * 32 + g * 8];
      #pragma unroll
      for (int f = 0; f < 4; ++f) {
        const short8v bv = *(const short8v*)&VT_lds[(16 * f + ln) * KSTR + st * 32 + g * 8];
        o[0][f] = __builtin_amdgcn_mfma_f32_16x16x32_bf16(ap0, bv, o[0][f], 0, 0, 0);
        o[1][f] = __builtin_amdgcn_mfma_f32_16x16x32_bf16(ap1, bv, o[1][f], 0, 0, 0);
      }
    }
  }
  #pragma unroll
  for (int m = 0; m < 2; ++m) {
    float inv[4];
    #pragma unroll
    for (int i = 0; i < 4; ++i) inv[i] = 1.0f / lrow[m][i];
    #pragma unroll
    for (int f = 0; f < 4; ++f) {
      #pragma unroll
      for (int i = 0; i < 4; ++i) {
        const size_t row = (size_t)bh * SLEN + q0 + w * 32 + m * 16 + g * 4 + i;
        Og[row * DDIM + 16 * f + ln] = o[m][f][i] * inv[i];
      }
    }
  }
}

extern "C" void kernel_launch(void* const* d_in, const int* in_sizes, int n_in,
                              void* d_out, int out_size, void* d_ws, size_t ws_size,
                              hipStream_t stream) {
  const float* Q = (const float*)d_in[0];
  const float* K = (const float*)d_in[1];
  const float* V = (const float*)d_in[2];
  const int*  vl = (const int*)d_in[3];
  float* out = (float*)d_out;

  const size_t ws_kv  = (size_t)2 * NBH * SLEN * DDIM * 2;     // 33,554,432 B (K+V bf16)
  const size_t ws_cs  = ws_kv + (size_t)NBH * 16 * 64 * 4;     // +524,288 B (chunk colsums)
  const size_t ws_all = ws_cs + 8 * 16 * 4;                    // +512 B (LPT sort table)

  if (ws_size >= ws_kv) {
    unsigned short* wsK  = (unsigned short*)d_ws;
    unsigned short* wsVT = wsK + (size_t)NBH * SLEN * DDIM;
    float* CS = (ws_size >= ws_all) ? (float*)((char*)d_ws + ws_kv) : nullptr;
    int*  SRT = CS ? (int*)((char*)d_ws + ws_cs) : nullptr;
    prep_kv<<<4608, 256, 0, stream>>>(K, V, wsK, wsVT, CS, vl, CS ? 1 : 0);
    if (CS) prep_sv<<<NBH + 1, 64, 0, stream>>>(CS, vl, SRT);
    attn_main<<<dim3(1024), dim3(256), 0, stream>>>(Q, wsK, wsVT, CS, SRT, vl, out);
  } else {
    attn_fwd_fallback<<<dim3(SLEN / 128, NBH), dim3(256), 0, stream>>>(Q, K, V, vl, out);
  }
}

// Round 7
// 160.616 us; speedup vs baseline: 1.3334x; 1.1095x over previous
//
#include <hip/hip_runtime.h>
#include <hip/hip_bf16.h>

typedef short short4v __attribute__((ext_vector_type(4)));
typedef short short8v __attribute__((ext_vector_type(8)));
typedef float floatx4 __attribute__((ext_vector_type(4)));

#define SLEN 1024
#define DDIM 64
#define NBH  128
#define PSTR 72   // P_lds key-stride (64 + 8): b64 stores & b128 reads bank-optimal

__device__ __forceinline__ unsigned short f2bf(float f) {
  union { float f; unsigned int u; } v; v.f = f;
  unsigned int u = v.u;
  u += 0x7fffu + ((u >> 16) & 1u);   // RNE
  return (unsigned short)(u >> 16);
}

// packed fp32x2 -> bf16x2 (RNE); low short = first arg
__device__ __forceinline__ unsigned int pkbf(float a, float b) {
  __hip_bfloat162 h = __float22bfloat162_rn(float2{a, b});
  union { __hip_bfloat162 h; unsigned int u; } c; c.h = h;
  return c.u;
}

__device__ __forceinline__ int decode_vl(const int* __restrict__ vraw, int bh) {
  const bool is64 = (vraw[1] == 0) && (vraw[3] == 0) && (vraw[5] == 0) && (vraw[7] == 0);
  const int b = bh >> 4;
  return is64 ? vraw[2 * b] : vraw[b];
}

// ---- prepass 1: per-(bh,ch) colsums of V fp32, only for fully/partially masked
//      tail chunks (ch >= tail_start); others write 0 (cheap). 2048 blocks x 1 wave.
__global__ __launch_bounds__(64)
void prep_cs(const float* __restrict__ Vg, float* __restrict__ CS,
             const int* __restrict__ vraw) {
  const int tile = blockIdx.x;                 // (bh,ch)
  const int bh = tile >> 4, ch = tile & 15;
  const int d = threadIdx.x;
  const int vl = decode_vl(vraw, bh);
  const int ts = (vl >> 6) + ((vl & 63) ? 1 : 0);
  float sum = 0.f;
  if (ch >= ts) {
    const float* src = Vg + (size_t)(bh * SLEN + ch * 64) * DDIM + d;
    float s0 = 0.f, s1 = 0.f, s2 = 0.f, s3 = 0.f;
    #pragma unroll
    for (int k = 0; k < 64; k += 4) {
      s0 += src[(size_t)(k + 0) * DDIM];
      s1 += src[(size_t)(k + 1) * DDIM];
      s2 += src[(size_t)(k + 2) * DDIM];
      s3 += src[(size_t)(k + 3) * DDIM];
    }
    sum = (s0 + s1) + (s2 + s3);
  }
  CS[(size_t)tile * 64 + d] = sum;
}

// ---- prepass 2: (a) blocks 0..127: colsums -> suffix sums; (b) block 128: LPT sort ----
// SRT[x*16 + rank] = bh with rank-th largest nch among {bh : bh%8 == x}.
__global__ __launch_bounds__(64)
void prep_sv(float* __restrict__ CS, const int* __restrict__ vraw, int* __restrict__ SRT) {
  const int blk = blockIdx.x;
  if (blk < NBH) {
    const int d = threadIdx.x;
    float acc = 0.f;
    for (int ch = 15; ch >= 0; --ch) {
      const size_t idx = ((size_t)blk * 16 + ch) * 64 + d;
      acc += CS[idx];
      CS[idx] = acc;
    }
  } else {
    const int x = threadIdx.x;
    if (x < 8) {
      int key[16];
      #pragma unroll
      for (int k = 0; k < 16; ++k) {
        const int vv = decode_vl(vraw, x + 8 * k);
        key[k] = (vv >> 6) + ((vv & 63) ? 1 : 0);
      }
      #pragma unroll
      for (int i = 0; i < 16; ++i) {
        int rank = 0;
        #pragma unroll
        for (int k2 = 0; k2 < 16; ++k2)
          rank += (int)((key[k2] > key[i]) || (key[k2] == key[i] && k2 < i));
        SRT[x * 16 + rank] = x + 8 * i;
      }
    }
  }
}

// ---------------- main: fused flash attention, no-max softmax ----------------
// K/V workspace ELIMINATED: each block stages fp32 K/V -> bf16 swizzled LDS itself.
// T14 async split: loads for chunk ch+2 issued before compute of ch (full-iteration
// hiding); convert+ds_write of ch+1 right after the barrier. LDS layout identical to
// the old DMA'd workspace, so the compute section is byte-for-byte the proven one.
__global__ __launch_bounds__(256)
void attn_main(const float* __restrict__ Qg, const float* __restrict__ Kg,
               const float* __restrict__ Vg, const float* __restrict__ SV,
               const int* __restrict__ SRT, const int* __restrict__ vraw,
               float* __restrict__ Og)
{
  __shared__ unsigned short K_lds[2][4096];     // 64x64 bf16 swizzled, double-buffered
  __shared__ unsigned short VT_lds[2][4096];
  __shared__ unsigned short P_lds[4][32 * PSTR];// per-wave P^T: [q][key]

  const int t  = threadIdx.x;
  const int w  = t >> 6;
  const int ln = t & 15;
  const int g  = (t >> 4) & 3;

  // task decode: XCD-local + LPT snake (proven in R6: FETCH 73->23MB, attn 44.7us)
  int bh, q0;
  if (SRT) {
    const int xcd  = blockIdx.x & 7;
    const int lidx = blockIdx.x >> 3;
    const int cu   = lidx & 31;
    const int j    = lidx >> 5;                       // 0..3
    const int r    = j * 32 + ((j & 1) ? (31 - cu) : cu);
    bh = SRT[xcd * 16 + (r >> 3)];
    q0 = (r & 7) * 128;
  } else {
    bh = blockIdx.x & 127;
    q0 = (blockIdx.x >> 7) * 128;
  }

  const int vl          = decode_vl(vraw, bh);
  const int full_ch     = vl >> 6;                 // chunks with all keys valid
  const int has_partial = (vl & 63) ? 1 : 0;
  const int nch         = SV ? (full_ch + has_partial) : 16;
  const int tail_start  = full_ch + has_partial;   // first fully-masked chunk

  // Q as B-operand fragments, pre-scaled by (1/8)*log2(e) so softmax = exp2.
  const float qs = 0.125f * 1.44269504f;
  short8v bq[2][2];
  #pragma unroll
  for (int nt = 0; nt < 2; ++nt) {
    const float* qp = Qg + ((size_t)bh * SLEN + q0 + w * 32 + nt * 16 + ln) * DDIM;
    #pragma unroll
    for (int st = 0; st < 2; ++st) {
      const float4 f0 = *(const float4*)(qp + st * 32 + g * 8);
      const float4 f1 = *(const float4*)(qp + st * 32 + g * 8 + 4);
      short8v a;
      a[0]=(short)f2bf(f0.x*qs); a[1]=(short)f2bf(f0.y*qs);
      a[2]=(short)f2bf(f0.z*qs); a[3]=(short)f2bf(f0.w*qs);
      a[4]=(short)f2bf(f1.x*qs); a[5]=(short)f2bf(f1.y*qs);
      a[6]=(short)f2bf(f1.z*qs); a[7]=(short)f2bf(f1.w*qs);
      bq[nt][st] = a;
    }
  }

  const int l7  = ln & 7;
  const int sw0 = ((g) ^ l7) * 8;
  const int sw1 = ((4 + g) ^ l7) * 8;

  short8v ones;   // bf16 1.0 x8 : B-operand for row-sum MFMA
  #pragma unroll
  for (int j = 0; j < 8; ++j) ones[j] = (short)0x3F80;

  floatx4 o[2][4], lacc[2];
  #pragma unroll
  for (int m = 0; m < 2; ++m) {
    lacc[m] = (floatx4){0.f, 0.f, 0.f, 0.f};
    #pragma unroll
    for (int f = 0; f < 4; ++f) o[m][f] = (floatx4){0.f, 0.f, 0.f, 0.f};
  }

  // ---- staging registers (32 VGPR): K granules q=t,t+256; V granules (gv,dv),(gv,dv+32)
  float kr[2][8];
  float vlo[8], vhi[8];
  const int dv = t & 31;          // V column pair (dv, dv+32)
  const int gv = t >> 5;          // V key-granule 0..7

  const float* kbB = Kg + (size_t)bh * SLEN * DDIM;
  const float* vbB = Vg + (size_t)bh * SLEN * DDIM;

  auto stage_load = [&](int ch) {
    const float* kb_ = kbB + (size_t)ch * 64 * DDIM;
    const float* vb_ = vbB + (size_t)ch * 64 * DDIM;
    #pragma unroll
    for (int h = 0; h < 2; ++h) {
      const int q = t + h * 256;
      const int r = q >> 3, gr = q & 7;         // K row r, granule gr
      const float4 f0 = *(const float4*)(kb_ + r * DDIM + gr * 8);
      const float4 f1 = *(const float4*)(kb_ + r * DDIM + gr * 8 + 4);
      kr[h][0]=f0.x; kr[h][1]=f0.y; kr[h][2]=f0.z; kr[h][3]=f0.w;
      kr[h][4]=f1.x; kr[h][5]=f1.y; kr[h][6]=f1.z; kr[h][7]=f1.w;
    }
    #pragma unroll
    for (int j = 0; j < 8; ++j) {               // coalesced: lanes 0..31 = dv 0..31
      vlo[j] = vb_[(gv * 8 + j) * DDIM + dv];
      vhi[j] = vb_[(gv * 8 + j) * DDIM + dv + 32];
    }
  };
  auto stage_write = [&](int b) {
    #pragma unroll
    for (int h = 0; h < 2; ++h) {
      const int q = t + h * 256;
      const int r = q >> 3, gr = q & 7;
      union { short8v s; unsigned int u[4]; } ks;
      ks.u[0] = pkbf(kr[h][0], kr[h][1]);
      ks.u[1] = pkbf(kr[h][2], kr[h][3]);
      ks.u[2] = pkbf(kr[h][4], kr[h][5]);
      ks.u[3] = pkbf(kr[h][6], kr[h][7]);
      *(short8v*)&K_lds[b][r * 64 + ((gr ^ (r & 7)) * 8)] = ks.s;   // conflict-free
    }
    union { short8v s; unsigned int u[4]; } va, vb2;
    va.u[0]  = pkbf(vlo[0], vlo[1]); va.u[1]  = pkbf(vlo[2], vlo[3]);
    va.u[2]  = pkbf(vlo[4], vlo[5]); va.u[3]  = pkbf(vlo[6], vlo[7]);
    vb2.u[0] = pkbf(vhi[0], vhi[1]); vb2.u[1] = pkbf(vhi[2], vhi[3]);
    vb2.u[2] = pkbf(vhi[4], vhi[5]); vb2.u[3] = pkbf(vhi[6], vhi[7]);
    const int swv = (gv ^ (dv & 7)) * 8;        // (dv+32)&7 == dv&7
    *(short8v*)&VT_lds[b][dv * 64 + swv] = va.s;          // conflict-free: 8-lane
    *(short8v*)&VT_lds[b][(dv + 32) * 64 + swv] = vb2.s;  // groups cover 32 banks
  };

  // prologue: chunk 0 staged sync; chunk 1 loads in flight across the barrier
  if (nch > 0) {
    stage_load(0);
    stage_write(0);                 // compiler inserts vmcnt waits for reg deps
    if (nch > 1) stage_load(1);
    asm volatile("s_waitcnt lgkmcnt(0)" ::: "memory");
    __builtin_amdgcn_s_barrier();
    asm volatile("" ::: "memory");
  }

  for (int ch = 0; ch < nch; ++ch) {
    const int b = ch & 1;
    // write chunk ch+1 (regs loaded one full iteration ago -> latency hidden);
    // buffer b^1's readers (chunk ch-1) finished at the previous barrier.
    if (ch + 1 < nch) stage_write(b ^ 1);
    if (ch + 2 < nch) stage_load(ch + 2);      // issue early; hides under compute

    // ---- S^T = K * Q^T : lane reg i holds key = mt*16+g*4+i, q = nt*16+ln ----
    floatx4 c[4][2];
    __builtin_amdgcn_s_setprio(1);
    #pragma unroll
    for (int mt = 0; mt < 4; ++mt) {
      const short8v a0 = *(const short8v*)&K_lds[b][(mt * 16 + ln) * 64 + sw0];
      const short8v a1 = *(const short8v*)&K_lds[b][(mt * 16 + ln) * 64 + sw1];
      #pragma unroll
      for (int nt = 0; nt < 2; ++nt) {
        floatx4 acc = (floatx4){0.f, 0.f, 0.f, 0.f};
        acc = __builtin_amdgcn_mfma_f32_16x16x32_bf16(a0, bq[nt][0], acc, 0, 0, 0);
        acc = __builtin_amdgcn_mfma_f32_16x16x32_bf16(a1, bq[nt][1], acc, 0, 0, 0);
        c[mt][nt] = acc;
      }
    }
    __builtin_amdgcn_s_setprio(0);

    // ---- p = exp2(s) (masked -> exp2(0) = 1.0), packed cvt, b64 stores ----
    const bool fullv = (ch < full_ch);
    #pragma unroll
    for (int mt = 0; mt < 4; ++mt) {
      const int kg = ch * 64 + mt * 16 + g * 4;
      #pragma unroll
      for (int nt = 0; nt < 2; ++nt) {
        float p[4];
        if (fullv) {
          #pragma unroll
          for (int i = 0; i < 4; ++i) p[i] = __builtin_amdgcn_exp2f(c[mt][nt][i]);
        } else {
          #pragma unroll
          for (int i = 0; i < 4; ++i) {
            const float x = (kg + i < vl) ? c[mt][nt][i] : 0.0f;
            p[i] = __builtin_amdgcn_exp2f(x);
          }
        }
        union { short4v v; unsigned int u[2]; } pk;
        pk.u[0] = pkbf(p[0], p[1]);
        pk.u[1] = pkbf(p[2], p[3]);
        *(short4v*)&P_lds[w][(nt * 16 + ln) * PSTR + mt * 16 + g * 4] = pk.v;
      }
    }

    // ---- O += P*V ; l += P*ones (row-sum in C-layout, matches O rows) ----
    #pragma unroll
    for (int st = 0; st < 2; ++st) {
      const short8v ap0 = *(const short8v*)&P_lds[w][(ln)      * PSTR + st * 32 + g * 8];
      const short8v ap1 = *(const short8v*)&P_lds[w][(16 + ln) * PSTR + st * 32 + g * 8];
      __builtin_amdgcn_s_setprio(1);
      lacc[0] = __builtin_amdgcn_mfma_f32_16x16x32_bf16(ap0, ones, lacc[0], 0, 0, 0);
      lacc[1] = __builtin_amdgcn_mfma_f32_16x16x32_bf16(ap1, ones, lacc[1], 0, 0, 0);
      const int sw = (st == 0) ? sw0 : sw1;
      #pragma unroll
      for (int f = 0; f < 4; ++f) {
        const short8v bv = *(const short8v*)&VT_lds[b][(f * 16 + ln) * 64 + sw];
        o[0][f] = __builtin_amdgcn_mfma_f32_16x16x32_bf16(ap0, bv, o[0][f], 0, 0, 0);
        o[1][f] = __builtin_amdgcn_mfma_f32_16x16x32_bf16(ap1, bv, o[1][f], 0, 0, 0);
      }
      __builtin_amdgcn_s_setprio(0);
    }

    if (ch + 1 < nch) {
      // publish chunk ch+1's LDS writes; reads of buf b done before next overwrite
      asm volatile("s_waitcnt lgkmcnt(0)" ::: "memory");
      __builtin_amdgcn_s_barrier();
      asm volatile("" ::: "memory");
    }
  }

  // ---- fully-masked tail: O += suffix colsum of V, l += #masked (p = 1.0 each) ----
  if (SV != nullptr && tail_start < 16) {
    const float* sv = SV + ((size_t)bh * 16 + tail_start) * 64;
    float svf[4];
    #pragma unroll
    for (int f = 0; f < 4; ++f) svf[f] = sv[f * 16 + ln];
    const float ml = (float)(SLEN - tail_start * 64);
    #pragma unroll
    for (int m = 0; m < 2; ++m) {
      #pragma unroll
      for (int i = 0; i < 4; ++i) lacc[m][i] += ml;
      #pragma unroll
      for (int f = 0; f < 4; ++f)
        #pragma unroll
        for (int i = 0; i < 4; ++i) o[m][f][i] += svf[f];
    }
  }

  // ---- epilogue: O /= l (lacc is in C-layout: same rows as O, no LDS needed) ----
  #pragma unroll
  for (int m = 0; m < 2; ++m) {
    #pragma unroll
    for (int i = 0; i < 4; ++i) {
      const float inv = 1.0f / lacc[m][i];
      const size_t row = (size_t)bh * SLEN + q0 + w * 32 + m * 16 + g * 4 + i;
      #pragma unroll
      for (int f = 0; f < 4; ++f)
        Og[row * DDIM + f * 16 + ln] = o[m][f][i] * inv;
    }
  }
}

extern "C" void kernel_launch(void* const* d_in, const int* in_sizes, int n_in,
                              void* d_out, int out_size, void* d_ws, size_t ws_size,
                              hipStream_t stream) {
  const float* Q = (const float*)d_in[0];
  const float* K = (const float*)d_in[1];
  const float* V = (const float*)d_in[2];
  const int*  vl = (const int*)d_in[3];
  float* out = (float*)d_out;

  const size_t ws_cs  = (size_t)NBH * 16 * 64 * 4;     // 524,288 B (chunk colsums)
  const size_t ws_all = ws_cs + 8 * 16 * 4;            // +512 B (LPT sort table)

  if (ws_size >= ws_all) {
    float* CS = (float*)d_ws;
    int*  SRT = (int*)((char*)d_ws + ws_cs);
    prep_cs<<<2048, 64, 0, stream>>>(V, CS, vl);
    prep_sv<<<NBH + 1, 64, 0, stream>>>(CS, vl, SRT);
    attn_main<<<dim3(1024), dim3(256), 0, stream>>>(Q, K, V, CS, SRT, vl, out);
  } else {
    // no workspace: process all 16 chunks, plain mapping (still correct)
    attn_main<<<dim3(1024), dim3(256), 0, stream>>>(Q, K, V, nullptr, nullptr, vl, out);
  }
}

// Round 8
// 160.531 us; speedup vs baseline: 1.3341x; 1.0005x over previous
//
#include <hip/hip_runtime.h>
#include <hip/hip_bf16.h>

typedef short short4v __attribute__((ext_vector_type(4)));
typedef short short8v __attribute__((ext_vector_type(8)));
typedef float floatx4 __attribute__((ext_vector_type(4)));
typedef unsigned int uint2v __attribute__((ext_vector_type(2)));

#define SLEN 1024
#define DDIM 64
#define NBH  128

__device__ __forceinline__ unsigned short f2bf(float f) {
  union { float f; unsigned int u; } v; v.f = f;
  unsigned int u = v.u;
  u += 0x7fffu + ((u >> 16) & 1u);   // RNE
  return (unsigned short)(u >> 16);
}

// packed fp32x2 -> bf16x2 (RNE); low short = first arg
__device__ __forceinline__ unsigned int pkbf(float a, float b) {
  __hip_bfloat162 h = __float22bfloat162_rn(float2{a, b});
  union { __hip_bfloat162 h; unsigned int u; } c; c.h = h;
  return c.u;
}

// cross-lane riffles (gfx950): a,b both updated. Verified in R3 (harness-passed).
__device__ __forceinline__ void pl32sw(unsigned int &a, unsigned int &b) {
#if __has_builtin(__builtin_amdgcn_permlane32_swap)
  uint2v r = __builtin_amdgcn_permlane32_swap(a, b, false, false);
  a = r[0]; b = r[1];
#else
  asm volatile("s_nop 1\n\tv_permlane32_swap_b32 %0, %1" : "+v"(a), "+v"(b));
#endif
}
__device__ __forceinline__ void pl16sw(unsigned int &a, unsigned int &b) {
#if __has_builtin(__builtin_amdgcn_permlane16_swap)
  uint2v r = __builtin_amdgcn_permlane16_swap(a, b, false, false);
  a = r[0]; b = r[1];
#else
  asm volatile("s_nop 1\n\tv_permlane16_swap_b32 %0, %1" : "+v"(a), "+v"(b));
#endif
}

__device__ __forceinline__ int decode_vl(const int* __restrict__ vraw, int bh) {
  const bool is64 = (vraw[1] == 0) && (vraw[3] == 0) && (vraw[5] == 0) && (vraw[7] == 0);
  const int b = bh >> 4;
  return is64 ? vraw[2 * b] : vraw[b];
}

// ---- prepass 1: per-(bh,ch) colsums of V fp32 for tail chunks only ----
__global__ __launch_bounds__(64)
void prep_cs(const float* __restrict__ Vg, float* __restrict__ CS,
             const int* __restrict__ vraw) {
  const int tile = blockIdx.x;                 // (bh,ch)
  const int bh = tile >> 4, ch = tile & 15;
  const int d = threadIdx.x;
  const int vl = decode_vl(vraw, bh);
  const int ts = (vl >> 6) + ((vl & 63) ? 1 : 0);
  float sum = 0.f;
  if (ch >= ts) {
    const float* src = Vg + (size_t)(bh * SLEN + ch * 64) * DDIM + d;
    float s0 = 0.f, s1 = 0.f, s2 = 0.f, s3 = 0.f;
    #pragma unroll
    for (int k = 0; k < 64; k += 4) {
      s0 += src[(size_t)(k + 0) * DDIM];
      s1 += src[(size_t)(k + 1) * DDIM];
      s2 += src[(size_t)(k + 2) * DDIM];
      s3 += src[(size_t)(k + 3) * DDIM];
    }
    sum = (s0 + s1) + (s2 + s3);
  }
  CS[(size_t)tile * 64 + d] = sum;
}

// ---- prepass 2: (a) blocks 0..127: colsums -> suffix sums; (b) block 128: LPT sort ----
__global__ __launch_bounds__(64)
void prep_sv(float* __restrict__ CS, const int* __restrict__ vraw, int* __restrict__ SRT) {
  const int blk = blockIdx.x;
  if (blk < NBH) {
    const int d = threadIdx.x;
    float acc = 0.f;
    for (int ch = 15; ch >= 0; --ch) {
      const size_t idx = ((size_t)blk * 16 + ch) * 64 + d;
      acc += CS[idx];
      CS[idx] = acc;
    }
  } else {
    const int x = threadIdx.x;
    if (x < 8) {
      int key[16];
      #pragma unroll
      for (int k = 0; k < 16; ++k) {
        const int vv = decode_vl(vraw, x + 8 * k);
        key[k] = (vv >> 6) + ((vv & 63) ? 1 : 0);
      }
      #pragma unroll
      for (int i = 0; i < 16; ++i) {
        int rank = 0;
        #pragma unroll
        for (int k2 = 0; k2 < 16; ++k2)
          rank += (int)((key[k2] > key[i]) || (key[k2] == key[i] && k2 < i));
        SRT[x * 16 + rank] = x + 8 * i;
      }
    }
  }
}

// ---------------- main: fused flash attention, no-max softmax ----------------
// R7 fused fp32->bf16 staging + R3 permlane in-register P (no P_lds!):
// LDS 51200->32768 B => 4+ blocks/CU resident (was 3); bank conflicts -> 0.
// PV computed as O^T = V^T * P^T; epilogue writes coalesced float4.
__global__ __launch_bounds__(256)
void attn_main(const float* __restrict__ Qg, const float* __restrict__ Kg,
               const float* __restrict__ Vg, const float* __restrict__ SV,
               const int* __restrict__ SRT, const int* __restrict__ vraw,
               float* __restrict__ Og)
{
  __shared__ unsigned short K_lds[2][4096];     // 64x64 bf16 swizzled, double-buffered
  __shared__ unsigned short VT_lds[2][4096];    // total 32 KB

  const int t  = threadIdx.x;
  const int ww = t >> 6;
  const int ln = t & 15;
  const int g  = (t >> 4) & 3;

  // task decode: XCD-local + LPT snake (R6-proven: FETCH 73->23MB)
  int bh, q0;
  if (SRT) {
    const int xcd  = blockIdx.x & 7;
    const int lidx = blockIdx.x >> 3;
    const int cu   = lidx & 31;
    const int j    = lidx >> 5;                       // 0..3
    const int r    = j * 32 + ((j & 1) ? (31 - cu) : cu);
    bh = SRT[xcd * 16 + (r >> 3)];
    q0 = (r & 7) * 128;
  } else {
    bh = blockIdx.x & 127;
    q0 = (blockIdx.x >> 7) * 128;
  }

  const int vl          = decode_vl(vraw, bh);
  const int full_ch     = vl >> 6;
  const int has_partial = (vl & 63) ? 1 : 0;
  const int nch         = SV ? (full_ch + has_partial) : 16;
  const int tail_start  = full_ch + has_partial;

  // Q as B-operand fragments, pre-scaled by (1/8)*log2(e) so softmax = exp2.
  const float qs = 0.125f * 1.44269504f;
  short8v bq[2][2];
  #pragma unroll
  for (int nt = 0; nt < 2; ++nt) {
    const float* qp = Qg + ((size_t)bh * SLEN + q0 + ww * 32 + nt * 16 + ln) * DDIM;
    #pragma unroll
    for (int st = 0; st < 2; ++st) {
      const float4 f0 = *(const float4*)(qp + st * 32 + g * 8);
      const float4 f1 = *(const float4*)(qp + st * 32 + g * 8 + 4);
      short8v a;
      a[0]=(short)f2bf(f0.x*qs); a[1]=(short)f2bf(f0.y*qs);
      a[2]=(short)f2bf(f0.z*qs); a[3]=(short)f2bf(f0.w*qs);
      a[4]=(short)f2bf(f1.x*qs); a[5]=(short)f2bf(f1.y*qs);
      a[6]=(short)f2bf(f1.z*qs); a[7]=(short)f2bf(f1.w*qs);
      bq[nt][st] = a;
    }
  }

  const int l7  = ln & 7;
  const int sw0 = ((g) ^ l7) * 8;       // granule g   (keys/d 0..31 half)
  const int sw1 = ((4 + g) ^ l7) * 8;   // granule 4+g (keys/d 32..63 half)

  short8v ones;   // bf16 1.0 x8 : A-operand for row-sum MFMA (all rows equal)
  #pragma unroll
  for (int j = 0; j < 8; ++j) ones[j] = (short)0x3F80;

  // O^T fragments: ot[nt][f] holds O^T[d = f*16 + g*4 + i][q = nt*16 + ln]
  floatx4 ot[2][4], lacc[2];
  #pragma unroll
  for (int m = 0; m < 2; ++m) {
    lacc[m] = (floatx4){0.f, 0.f, 0.f, 0.f};
    #pragma unroll
    for (int f = 0; f < 4; ++f) ot[m][f] = (floatx4){0.f, 0.f, 0.f, 0.f};
  }

  // ---- staging registers: K granules q=t,t+256; V col-pairs (gv,dv),(gv,dv+32) ----
  float kr[2][8];
  float vlo[8], vhi[8];
  const int dv = t & 31;
  const int gv = t >> 5;

  const float* kbB = Kg + (size_t)bh * SLEN * DDIM;
  const float* vbB = Vg + (size_t)bh * SLEN * DDIM;

  auto stage_load = [&](int ch) {
    const float* kb_ = kbB + (size_t)ch * 64 * DDIM;
    const float* vb_ = vbB + (size_t)ch * 64 * DDIM;
    #pragma unroll
    for (int h = 0; h < 2; ++h) {
      const int q = t + h * 256;
      const int r = q >> 3, gr = q & 7;
      const float4 f0 = *(const float4*)(kb_ + r * DDIM + gr * 8);
      const float4 f1 = *(const float4*)(kb_ + r * DDIM + gr * 8 + 4);
      kr[h][0]=f0.x; kr[h][1]=f0.y; kr[h][2]=f0.z; kr[h][3]=f0.w;
      kr[h][4]=f1.x; kr[h][5]=f1.y; kr[h][6]=f1.z; kr[h][7]=f1.w;
    }
    #pragma unroll
    for (int j = 0; j < 8; ++j) {
      vlo[j] = vb_[(gv * 8 + j) * DDIM + dv];
      vhi[j] = vb_[(gv * 8 + j) * DDIM + dv + 32];
    }
  };
  auto stage_write = [&](int b) {
    #pragma unroll
    for (int h = 0; h < 2; ++h) {
      const int q = t + h * 256;
      const int r = q >> 3, gr = q & 7;
      union { short8v s; unsigned int u[4]; } ks;
      ks.u[0] = pkbf(kr[h][0], kr[h][1]);
      ks.u[1] = pkbf(kr[h][2], kr[h][3]);
      ks.u[2] = pkbf(kr[h][4], kr[h][5]);
      ks.u[3] = pkbf(kr[h][6], kr[h][7]);
      *(short8v*)&K_lds[b][r * 64 + ((gr ^ (r & 7)) * 8)] = ks.s;
    }
    union { short8v s; unsigned int u[4]; } va, vb2;
    va.u[0]  = pkbf(vlo[0], vlo[1]); va.u[1]  = pkbf(vlo[2], vlo[3]);
    va.u[2]  = pkbf(vlo[4], vlo[5]); va.u[3]  = pkbf(vlo[6], vlo[7]);
    vb2.u[0] = pkbf(vhi[0], vhi[1]); vb2.u[1] = pkbf(vhi[2], vhi[3]);
    vb2.u[2] = pkbf(vhi[4], vhi[5]); vb2.u[3] = pkbf(vhi[6], vhi[7]);
    const int swv = (gv ^ (dv & 7)) * 8;
    *(short8v*)&VT_lds[b][dv * 64 + swv] = va.s;
    *(short8v*)&VT_lds[b][(dv + 32) * 64 + swv] = vb2.s;
  };

  // prologue: chunk 0 staged sync; chunk 1 loads in flight across the barrier
  if (nch > 0) {
    stage_load(0);
    stage_write(0);
    if (nch > 1) stage_load(1);
    asm volatile("s_waitcnt lgkmcnt(0)" ::: "memory");
    __builtin_amdgcn_s_barrier();
    asm volatile("" ::: "memory");
  }

  for (int ch = 0; ch < nch; ++ch) {
    const int b = ch & 1;
    if (ch + 1 < nch) stage_write(b ^ 1);     // regs loaded a full iteration ago
    if (ch + 2 < nch) stage_load(ch + 2);     // issue early; hides under compute

    // ---- S^T = K * Q^T : lane reg i holds key = mt*16+g*4+i, q = nt*16+ln ----
    floatx4 c[4][2];
    __builtin_amdgcn_s_setprio(1);
    #pragma unroll
    for (int mt = 0; mt < 4; ++mt) {
      const short8v a0 = *(const short8v*)&K_lds[b][(mt * 16 + ln) * 64 + sw0];
      const short8v a1 = *(const short8v*)&K_lds[b][(mt * 16 + ln) * 64 + sw1];
      #pragma unroll
      for (int nt = 0; nt < 2; ++nt) {
        floatx4 acc = (floatx4){0.f, 0.f, 0.f, 0.f};
        acc = __builtin_amdgcn_mfma_f32_16x16x32_bf16(a0, bq[nt][0], acc, 0, 0, 0);
        acc = __builtin_amdgcn_mfma_f32_16x16x32_bf16(a1, bq[nt][1], acc, 0, 0, 0);
        c[mt][nt] = acc;
      }
    }
    __builtin_amdgcn_s_setprio(0);

    // ---- p = exp2(s) (masked -> exp2(0) = 1.0), packed cvt to bf16 pairs ----
    unsigned int pk0[4][2], pk1[4][2];   // pk0 = keys {0,1}, pk1 = keys {2,3} of group
    const bool fullv = (ch < full_ch);
    #pragma unroll
    for (int mt = 0; mt < 4; ++mt) {
      const int kg = ch * 64 + mt * 16 + g * 4;
      #pragma unroll
      for (int nt = 0; nt < 2; ++nt) {
        float p[4];
        if (fullv) {
          #pragma unroll
          for (int i = 0; i < 4; ++i) p[i] = __builtin_amdgcn_exp2f(c[mt][nt][i]);
        } else {
          #pragma unroll
          for (int i = 0; i < 4; ++i) {
            const float x = (kg + i < vl) ? c[mt][nt][i] : 0.0f;
            p[i] = __builtin_amdgcn_exp2f(x);
          }
        }
        pk0[mt][nt] = pkbf(p[0], p[1]);
        pk1[mt][nt] = pkbf(p[2], p[3]);
      }
    }

    // ---- in-register P^T B-fragment build (permlane riffles, no LDS) ----
    // bp[st][nt]: lane(g,ln) holds P^T[k = st*32 + g*8 + j][q = nt*16 + ln], j=0..7
    short8v bp[2][2];
    #pragma unroll
    for (int st = 0; st < 2; ++st) {
      #pragma unroll
      for (int nt = 0; nt < 2; ++nt) {
        unsigned int a0 = pk0[2 * st][nt], b0 = pk0[2 * st + 1][nt];
        unsigned int a1 = pk1[2 * st][nt], b1 = pk1[2 * st + 1][nt];
        pl32sw(a0, b0); pl16sw(a0, b0);   // a0 -> keys {0,1}, b0 -> keys {4,5}
        pl32sw(a1, b1); pl16sw(a1, b1);   // a1 -> keys {2,3}, b1 -> keys {6,7}
        union { short8v s; unsigned int u[4]; } bb;
        bb.u[0] = a0; bb.u[1] = a1; bb.u[2] = b0; bb.u[3] = b1;
        bp[st][nt] = bb.s;
      }
    }

    // ---- O^T += V^T * P^T ; l += ones * P^T (all rows of lacc equal l_q) ----
    __builtin_amdgcn_s_setprio(1);
    #pragma unroll
    for (int st = 0; st < 2; ++st) {
      lacc[0] = __builtin_amdgcn_mfma_f32_16x16x32_bf16(ones, bp[st][0], lacc[0], 0, 0, 0);
      lacc[1] = __builtin_amdgcn_mfma_f32_16x16x32_bf16(ones, bp[st][1], lacc[1], 0, 0, 0);
      const int sw = (st == 0) ? sw0 : sw1;
      #pragma unroll
      for (int f = 0; f < 4; ++f) {
        const short8v av = *(const short8v*)&VT_lds[b][(f * 16 + ln) * 64 + sw];
        ot[0][f] = __builtin_amdgcn_mfma_f32_16x16x32_bf16(av, bp[st][0], ot[0][f], 0, 0, 0);
        ot[1][f] = __builtin_amdgcn_mfma_f32_16x16x32_bf16(av, bp[st][1], ot[1][f], 0, 0, 0);
      }
    }
    __builtin_amdgcn_s_setprio(0);

    if (ch + 1 < nch) {
      asm volatile("s_waitcnt lgkmcnt(0)" ::: "memory");
      __builtin_amdgcn_s_barrier();
      asm volatile("" ::: "memory");
    }
  }

  // ---- fully-masked tail: O^T += suffix colsum of V, l += #masked (p = 1.0 each) ----
  if (SV != nullptr && tail_start < 16) {
    const float* sv = SV + ((size_t)bh * 16 + tail_start) * 64 + g * 4;
    float4 sv4[4];
    #pragma unroll
    for (int f = 0; f < 4; ++f) sv4[f] = *(const float4*)(sv + f * 16);
    const float ml = (float)(SLEN - tail_start * 64);
    #pragma unroll
    for (int nt = 0; nt < 2; ++nt) {
      #pragma unroll
      for (int i = 0; i < 4; ++i) lacc[nt][i] += ml;
      #pragma unroll
      for (int f = 0; f < 4; ++f) {
        ot[nt][f][0] += sv4[f].x; ot[nt][f][1] += sv4[f].y;
        ot[nt][f][2] += sv4[f].z; ot[nt][f][3] += sv4[f].w;
      }
    }
  }

  // ---- epilogue: O = O^T / l ; lane writes float4 (4 consecutive d) per (nt,f) ----
  #pragma unroll
  for (int nt = 0; nt < 2; ++nt) {
    const float inv = 1.0f / lacc[nt][0];
    float* orow = Og + ((size_t)bh * SLEN + q0 + ww * 32 + nt * 16 + ln) * DDIM + g * 4;
    #pragma unroll
    for (int f = 0; f < 4; ++f) {
      float4 v4;
      v4.x = ot[nt][f][0] * inv; v4.y = ot[nt][f][1] * inv;
      v4.z = ot[nt][f][2] * inv; v4.w = ot[nt][f][3] * inv;
      *(float4*)(orow + f * 16) = v4;
    }
  }
}

extern "C" void kernel_launch(void* const* d_in, const int* in_sizes, int n_in,
                              void* d_out, int out_size, void* d_ws, size_t ws_size,
                              hipStream_t stream) {
  const float* Q = (const float*)d_in[0];
  const float* K = (const float*)d_in[1];
  const float* V = (const float*)d_in[2];
  const int*  vl = (const int*)d_in[3];
  float* out = (float*)d_out;

  const size_t ws_cs  = (size_t)NBH * 16 * 64 * 4;     // 524,288 B (chunk colsums)
  const size_t ws_all = ws_cs + 8 * 16 * 4;            // +512 B (LPT sort table)

  if (ws_size >= ws_all) {
    float* CS = (float*)d_ws;
    int*  SRT = (int*)((char*)d_ws + ws_cs);
    prep_cs<<<2048, 64, 0, stream>>>(V, CS, vl);
    prep_sv<<<NBH + 1, 64, 0, stream>>>(CS, vl, SRT);
    attn_main<<<dim3(1024), dim3(256), 0, stream>>>(Q, K, V, CS, SRT, vl, out);
  } else {
    attn_main<<<dim3(1024), dim3(256), 0, stream>>>(Q, K, V, nullptr, nullptr, vl, out);
  }
}